// Round 1
// baseline (1430.999 us; speedup 1.0000x reference)
//
#include <hip/hip_runtime.h>
#include <math.h>

// Problem constants
#define B_ 2
#define N_ 4096
#define C_ 256
#define H_ 4
#define DH_ 64
#define EPS_ 1e-6f
#define INV_DK_ 0.125f   // 1/sqrt(64)

// ---------------------------------------------------------------------------
// Kernel 1: h = LayerNorm(x + pos) * g + b      one block per row (B*N rows)
// ---------------------------------------------------------------------------
__global__ __launch_bounds__(256) void ln_kernel(
    const float* __restrict__ x, const float* __restrict__ pos,
    const float* __restrict__ g, const float* __restrict__ beta,
    float* __restrict__ hout) {
  const int row = blockIdx.x;
  const int t = threadIdx.x;
  float val = x[row * C_ + t] + pos[row * C_ + t];

  __shared__ float red[256];
  red[t] = val;
  __syncthreads();
  for (int s = 128; s > 0; s >>= 1) {
    if (t < s) red[t] += red[t + s];
    __syncthreads();
  }
  const float mu = red[0] * (1.0f / C_);
  __syncthreads();
  const float d = val - mu;
  red[t] = d * d;
  __syncthreads();
  for (int s = 128; s > 0; s >>= 1) {
    if (t < s) red[t] += red[t + s];
    __syncthreads();
  }
  const float var = red[0] * (1.0f / C_);
  hout[row * C_ + t] = d * rsqrtf(var + EPS_) * g[t] + beta[t];
}

// ---------------------------------------------------------------------------
// Kernel 2: q/k/v[b,h,n,d] = h @ W{q,k,v}[h] + b{q,k,v}[h]
// grid: (rowtiles=128, H, 3)   64x64 tile, 4x4 micro per thread
// ---------------------------------------------------------------------------
__global__ __launch_bounds__(256) void qkv_kernel(
    const float* __restrict__ hbuf,
    const float* __restrict__ Wq, const float* __restrict__ bq,
    const float* __restrict__ Wk, const float* __restrict__ bk,
    const float* __restrict__ Wv, const float* __restrict__ bv,
    float* __restrict__ qo, float* __restrict__ ko, float* __restrict__ vo) {
  const int rt = blockIdx.x;
  const int hh = blockIdx.y;
  const int mz = blockIdx.z;
  const float* W    = (mz == 0 ? Wq : mz == 1 ? Wk : Wv) + hh * C_ * DH_;
  const float* bias = (mz == 0 ? bq : mz == 1 ? bk : bv) + hh * DH_;
  float* outp       = (mz == 0 ? qo : mz == 1 ? ko : vo);

  __shared__ float As[64][68];   // [row][k]
  __shared__ float Ws[64][68];   // [k][d]
  const int t = threadIdx.x;
  const int cg = t & 15, rg = t >> 4;
  const int row0 = rt * 64;

  float acc[4][4] = {};
  for (int kt = 0; kt < C_; kt += 64) {
    __syncthreads();
    for (int e = t; e < 4096; e += 256) {
      As[e >> 6][e & 63] = hbuf[(row0 + (e >> 6)) * C_ + kt + (e & 63)];
      Ws[e >> 6][e & 63] = W[(kt + (e >> 6)) * DH_ + (e & 63)];
    }
    __syncthreads();
    for (int k4 = 0; k4 < 64; k4 += 4) {
      float4 a[4], w4[4];
#pragma unroll
      for (int i = 0; i < 4; i++) a[i] = *(const float4*)&As[rg * 4 + i][k4];
#pragma unroll
      for (int kk = 0; kk < 4; kk++) w4[kk] = *(const float4*)&Ws[k4 + kk][cg * 4];
#pragma unroll
      for (int i = 0; i < 4; i++) {
        acc[i][0] += a[i].x * w4[0].x + a[i].y * w4[1].x + a[i].z * w4[2].x + a[i].w * w4[3].x;
        acc[i][1] += a[i].x * w4[0].y + a[i].y * w4[1].y + a[i].z * w4[2].y + a[i].w * w4[3].y;
        acc[i][2] += a[i].x * w4[0].z + a[i].y * w4[1].z + a[i].z * w4[2].z + a[i].w * w4[3].z;
        acc[i][3] += a[i].x * w4[0].w + a[i].y * w4[1].w + a[i].z * w4[2].w + a[i].w * w4[3].w;
      }
    }
  }
#pragma unroll
  for (int i = 0; i < 4; i++) {
#pragma unroll
    for (int j = 0; j < 4; j++) {
      const int row = row0 + rg * 4 + i;
      const int b = row >> 12;          // row / N_
      const int n = row & (N_ - 1);
      const int col = cg * 4 + j;
      outp[(((size_t)(b * H_ + hh)) * N_ + n) * DH_ + col] = acc[i][j] + bias[col];
    }
  }
}

// ---------------------------------------------------------------------------
// Kernel 3: per-column softmax stats  m_j = max_i s_ij, l_j = sum_i exp(s-m)
// grid: (N/64, B*H). Block owns 64 columns, iterates all 4096 rows online.
// ---------------------------------------------------------------------------
__global__ __launch_bounds__(256) void colstats_kernel(
    const float* __restrict__ q, const float* __restrict__ k,
    float* __restrict__ mbuf, float* __restrict__ lbuf) {
  const int bh = blockIdx.y;
  const int j0 = blockIdx.x * 64;
  __shared__ float Ks[64][68];   // [j][d]
  __shared__ float Qs[64][68];   // [i][d]
  __shared__ float Ms[16][64];
  __shared__ float Ls[16][64];
  const int t = threadIdx.x;
  const int cg = t & 15, rg = t >> 4;

  for (int e = t; e < 4096; e += 256)
    Ks[e >> 6][e & 63] = k[((size_t)bh * N_ + j0 + (e >> 6)) * DH_ + (e & 63)];

  float mloc[4], lloc[4];
#pragma unroll
  for (int j = 0; j < 4; j++) { mloc[j] = -1e30f; lloc[j] = 0.0f; }

  for (int it = 0; it < N_ / 64; ++it) {
    __syncthreads();
    for (int e = t; e < 4096; e += 256)
      Qs[e >> 6][e & 63] = q[((size_t)bh * N_ + it * 64 + (e >> 6)) * DH_ + (e & 63)];
    __syncthreads();

    float acc[4][4] = {};
    for (int d4 = 0; d4 < 64; d4 += 4) {
      float4 a[4], b4[4];
#pragma unroll
      for (int i = 0; i < 4; i++) a[i] = *(const float4*)&Qs[rg * 4 + i][d4];
#pragma unroll
      for (int j = 0; j < 4; j++) b4[j] = *(const float4*)&Ks[cg * 4 + j][d4];
#pragma unroll
      for (int i = 0; i < 4; i++)
#pragma unroll
        for (int j = 0; j < 4; j++)
          acc[i][j] += a[i].x * b4[j].x + a[i].y * b4[j].y + a[i].z * b4[j].z + a[i].w * b4[j].w;
    }
#pragma unroll
    for (int j = 0; j < 4; j++) {
#pragma unroll
      for (int i = 0; i < 4; i++) {
        const float s = acc[i][j] * INV_DK_;
        const float mn = fmaxf(mloc[j], s);
        lloc[j] = lloc[j] * __expf(mloc[j] - mn) + __expf(s - mn);
        mloc[j] = mn;
      }
    }
  }
#pragma unroll
  for (int j = 0; j < 4; j++) { Ms[rg][cg * 4 + j] = mloc[j]; Ls[rg][cg * 4 + j] = lloc[j]; }
  __syncthreads();
  if (t < 64) {
    float m = -1e30f;
    for (int g2 = 0; g2 < 16; ++g2) m = fmaxf(m, Ms[g2][t]);
    float l = 0.0f;
    for (int g2 = 0; g2 < 16; ++g2) l += Ls[g2][t] * __expf(Ms[g2][t] - m);
    mbuf[(size_t)bh * N_ + j0 + t] = m;
    lbuf[(size_t)bh * N_ + j0 + t] = l;
  }
}

// ---------------------------------------------------------------------------
// Kernel 4: o[i,d] = sum_j exp(s_ij - m_j)/l_j * v[j,d]  (recompute scores)
// grid: (N/64, B*H). Writes o in [B,N,C] layout (head-concat on channel).
// ---------------------------------------------------------------------------
__global__ __launch_bounds__(256) void attnout_kernel(
    const float* __restrict__ q, const float* __restrict__ k,
    const float* __restrict__ v, const float* __restrict__ mbuf,
    const float* __restrict__ lbuf, float* __restrict__ obuf) {
  const int bh = blockIdx.y;
  const int b = bh / H_, hh = bh % H_;
  const int i0 = blockIdx.x * 64;
  __shared__ float Qs[64][68];
  __shared__ float Ks[64][68];
  __shared__ float Vs[64][68];
  __shared__ float Ps[64][68];
  __shared__ float mj_s[64], il_s[64];
  const int t = threadIdx.x;
  const int cg = t & 15, rg = t >> 4;

  for (int e = t; e < 4096; e += 256)
    Qs[e >> 6][e & 63] = q[((size_t)bh * N_ + i0 + (e >> 6)) * DH_ + (e & 63)];

  float oacc[4][4] = {};
  for (int jt = 0; jt < N_ / 64; ++jt) {
    __syncthreads();
    for (int e = t; e < 4096; e += 256) {
      Ks[e >> 6][e & 63] = k[((size_t)bh * N_ + jt * 64 + (e >> 6)) * DH_ + (e & 63)];
      Vs[e >> 6][e & 63] = v[((size_t)bh * N_ + jt * 64 + (e >> 6)) * DH_ + (e & 63)];
    }
    if (t < 64) {
      mj_s[t] = mbuf[(size_t)bh * N_ + jt * 64 + t];
      il_s[t] = 1.0f / lbuf[(size_t)bh * N_ + jt * 64 + t];
    }
    __syncthreads();

    // s tile: rows = queries i, cols = keys j
    float acc[4][4] = {};
    for (int d4 = 0; d4 < 64; d4 += 4) {
      float4 a[4], b4[4];
#pragma unroll
      for (int i = 0; i < 4; i++) a[i] = *(const float4*)&Qs[rg * 4 + i][d4];
#pragma unroll
      for (int j = 0; j < 4; j++) b4[j] = *(const float4*)&Ks[cg * 4 + j][d4];
#pragma unroll
      for (int i = 0; i < 4; i++)
#pragma unroll
        for (int j = 0; j < 4; j++)
          acc[i][j] += a[i].x * b4[j].x + a[i].y * b4[j].y + a[i].z * b4[j].z + a[i].w * b4[j].w;
    }
#pragma unroll
    for (int i = 0; i < 4; i++)
#pragma unroll
      for (int j = 0; j < 4; j++) {
        const int col = cg * 4 + j;
        Ps[rg * 4 + i][col] = __expf(acc[i][j] * INV_DK_ - mj_s[col]) * il_s[col];
      }
    __syncthreads();

    // oacc += Ps @ Vs   (reduce over jj; cols = d)
    for (int j4 = 0; j4 < 64; j4 += 4) {
      float4 p4[4], vr[4];
#pragma unroll
      for (int i = 0; i < 4; i++) p4[i] = *(const float4*)&Ps[rg * 4 + i][j4];
#pragma unroll
      for (int jj = 0; jj < 4; jj++) vr[jj] = *(const float4*)&Vs[j4 + jj][cg * 4];
#pragma unroll
      for (int i = 0; i < 4; i++) {
        oacc[i][0] += p4[i].x * vr[0].x + p4[i].y * vr[1].x + p4[i].z * vr[2].x + p4[i].w * vr[3].x;
        oacc[i][1] += p4[i].x * vr[0].y + p4[i].y * vr[1].y + p4[i].z * vr[2].y + p4[i].w * vr[3].y;
        oacc[i][2] += p4[i].x * vr[0].z + p4[i].y * vr[1].z + p4[i].z * vr[2].z + p4[i].w * vr[3].z;
        oacc[i][3] += p4[i].x * vr[0].w + p4[i].y * vr[1].w + p4[i].z * vr[2].w + p4[i].w * vr[3].w;
      }
    }
  }
#pragma unroll
  for (int i = 0; i < 4; i++)
#pragma unroll
    for (int j = 0; j < 4; j++)
      obuf[((size_t)b * N_ + i0 + rg * 4 + i) * C_ + hh * DH_ + cg * 4 + j] = oacc[i][j];
}

// ---------------------------------------------------------------------------
// Kernel 5: out = o @ Wo + bo    grid: (128, 4)
// ---------------------------------------------------------------------------
__global__ __launch_bounds__(256) void outproj_kernel(
    const float* __restrict__ obuf, const float* __restrict__ Wo,
    const float* __restrict__ bo, float* __restrict__ out) {
  const int rt = blockIdx.x, ct = blockIdx.y;
  __shared__ float As[64][68];
  __shared__ float Ws[64][68];
  const int t = threadIdx.x;
  const int cg = t & 15, rg = t >> 4;

  float acc[4][4] = {};
  for (int kt = 0; kt < C_; kt += 64) {
    __syncthreads();
    for (int e = t; e < 4096; e += 256) {
      As[e >> 6][e & 63] = obuf[((size_t)rt * 64 + (e >> 6)) * C_ + kt + (e & 63)];
      Ws[e >> 6][e & 63] = Wo[((size_t)kt + (e >> 6)) * C_ + ct * 64 + (e & 63)];
    }
    __syncthreads();
    for (int k4 = 0; k4 < 64; k4 += 4) {
      float4 a[4], w4[4];
#pragma unroll
      for (int i = 0; i < 4; i++) a[i] = *(const float4*)&As[rg * 4 + i][k4];
#pragma unroll
      for (int kk = 0; kk < 4; kk++) w4[kk] = *(const float4*)&Ws[k4 + kk][cg * 4];
#pragma unroll
      for (int i = 0; i < 4; i++) {
        acc[i][0] += a[i].x * w4[0].x + a[i].y * w4[1].x + a[i].z * w4[2].x + a[i].w * w4[3].x;
        acc[i][1] += a[i].x * w4[0].y + a[i].y * w4[1].y + a[i].z * w4[2].y + a[i].w * w4[3].y;
        acc[i][2] += a[i].x * w4[0].z + a[i].y * w4[1].z + a[i].z * w4[2].z + a[i].w * w4[3].z;
        acc[i][3] += a[i].x * w4[0].w + a[i].y * w4[1].w + a[i].z * w4[2].w + a[i].w * w4[3].w;
      }
    }
  }
#pragma unroll
  for (int i = 0; i < 4; i++)
#pragma unroll
    for (int j = 0; j < 4; j++) {
      const int col = ct * 64 + cg * 4 + j;
      out[((size_t)rt * 64 + rg * 4 + i) * C_ + col] = acc[i][j] + bo[col];
    }
}

// ---------------------------------------------------------------------------
extern "C" void kernel_launch(void* const* d_in, const int* in_sizes, int n_in,
                              void* d_out, int out_size, void* d_ws, size_t ws_size,
                              hipStream_t stream) {
  const float* x    = (const float*)d_in[0];
  const float* pos  = (const float*)d_in[1];
  const float* Wq   = (const float*)d_in[2];
  const float* bq   = (const float*)d_in[3];
  const float* Wk   = (const float*)d_in[4];
  const float* bk   = (const float*)d_in[5];
  const float* Wv   = (const float*)d_in[6];
  const float* bv   = (const float*)d_in[7];
  const float* Wo   = (const float*)d_in[8];
  const float* bo   = (const float*)d_in[9];
  const float* ln_g = (const float*)d_in[10];
  const float* ln_b = (const float*)d_in[11];
  float* out = (float*)d_out;

  // Workspace layout (floats): h, q, k, v, o each B*N*C = 2M; m, l each B*H*N = 32K
  float* ws   = (float*)d_ws;
  const size_t SZ = (size_t)B_ * N_ * C_;   // 2M elements
  float* hbuf = ws;
  float* qb   = hbuf + SZ;
  float* kb   = qb + SZ;
  float* vb   = kb + SZ;
  float* ob   = vb + SZ;
  float* mb   = ob + SZ;
  float* lb   = mb + (size_t)B_ * H_ * N_;

  ln_kernel<<<B_ * N_, 256, 0, stream>>>(x, pos, ln_g, ln_b, hbuf);
  qkv_kernel<<<dim3(B_ * N_ / 64, H_, 3), 256, 0, stream>>>(hbuf, Wq, bq, Wk, bk, Wv, bv, qb, kb, vb);
  colstats_kernel<<<dim3(N_ / 64, B_ * H_), 256, 0, stream>>>(qb, kb, mb, lb);
  attnout_kernel<<<dim3(N_ / 64, B_ * H_), 256, 0, stream>>>(qb, kb, vb, mb, lb, ob);
  outproj_kernel<<<dim3(B_ * N_ / 64, C_ / 64), 256, 0, stream>>>(ob, Wo, bo, out);
}

// Round 2
// 410.688 us; speedup vs baseline: 3.4844x; 3.4844x over previous
//
#include <hip/hip_runtime.h>
#include <math.h>

// Problem constants
#define B_ 2
#define N_ 4096
#define C_ 256
#define H_ 4
#define DH_ 64
#define EPS_ 1e-6f
#define INV_DK_ 0.125f   // 1/sqrt(64)

typedef short bf16x8 __attribute__((ext_vector_type(8)));   // 8 bf16 in 4 VGPRs
typedef float f32x4 __attribute__((ext_vector_type(4)));

__device__ __forceinline__ unsigned short f2bf(float x) {
  unsigned int u = __float_as_uint(x);
  return (unsigned short)((u + 0x7FFFu + ((u >> 16) & 1u)) >> 16);  // RNE
}

// ---------------------------------------------------------------------------
// Kernel 1: h = LayerNorm(x + pos) * g + b      one block per row (B*N rows)
// ---------------------------------------------------------------------------
__global__ __launch_bounds__(256) void ln_kernel(
    const float* __restrict__ x, const float* __restrict__ pos,
    const float* __restrict__ g, const float* __restrict__ beta,
    float* __restrict__ hout) {
  const int row = blockIdx.x;
  const int t = threadIdx.x;
  float val = x[row * C_ + t] + pos[row * C_ + t];

  __shared__ float red[256];
  red[t] = val;
  __syncthreads();
  for (int s = 128; s > 0; s >>= 1) {
    if (t < s) red[t] += red[t + s];
    __syncthreads();
  }
  const float mu = red[0] * (1.0f / C_);
  __syncthreads();
  const float d = val - mu;
  red[t] = d * d;
  __syncthreads();
  for (int s = 128; s > 0; s >>= 1) {
    if (t < s) red[t] += red[t + s];
    __syncthreads();
  }
  const float var = red[0] * (1.0f / C_);
  hout[row * C_ + t] = d * rsqrtf(var + EPS_) * g[t] + beta[t];
}

// ---------------------------------------------------------------------------
// Kernel 2: q/k/v projections (fp32 compute), emitting bf16:
//   q16,k16: [bh][n][64] row-major;  vT16: [bh][64][N] (transposed for PV B-frag)
// grid: (128, H, 3)
// ---------------------------------------------------------------------------
__global__ __launch_bounds__(256) void qkv_kernel(
    const float* __restrict__ hbuf,
    const float* __restrict__ Wq, const float* __restrict__ bq,
    const float* __restrict__ Wk, const float* __restrict__ bk,
    const float* __restrict__ Wv, const float* __restrict__ bv,
    unsigned short* __restrict__ q16, unsigned short* __restrict__ k16,
    unsigned short* __restrict__ vT16) {
  const int rt = blockIdx.x;
  const int hh = blockIdx.y;
  const int mz = blockIdx.z;
  const float* W    = (mz == 0 ? Wq : mz == 1 ? Wk : Wv) + hh * C_ * DH_;
  const float* bias = (mz == 0 ? bq : mz == 1 ? bk : bv) + hh * DH_;

  __shared__ float As[64][68];   // [row][k]
  __shared__ float Ws[64][68];   // [k][d]
  const int t = threadIdx.x;
  const int cg = t & 15, rg = t >> 4;
  const int row0 = rt * 64;

  float acc[4][4] = {};
  for (int kt = 0; kt < C_; kt += 64) {
    __syncthreads();
    for (int e = t; e < 4096; e += 256) {
      As[e >> 6][e & 63] = hbuf[(row0 + (e >> 6)) * C_ + kt + (e & 63)];
      Ws[e >> 6][e & 63] = W[(kt + (e >> 6)) * DH_ + (e & 63)];
    }
    __syncthreads();
    for (int k4 = 0; k4 < 64; k4 += 4) {
      float4 a[4], w4[4];
#pragma unroll
      for (int i = 0; i < 4; i++) a[i] = *(const float4*)&As[rg * 4 + i][k4];
#pragma unroll
      for (int kk = 0; kk < 4; kk++) w4[kk] = *(const float4*)&Ws[k4 + kk][cg * 4];
#pragma unroll
      for (int i = 0; i < 4; i++) {
        acc[i][0] += a[i].x * w4[0].x + a[i].y * w4[1].x + a[i].z * w4[2].x + a[i].w * w4[3].x;
        acc[i][1] += a[i].x * w4[0].y + a[i].y * w4[1].y + a[i].z * w4[2].y + a[i].w * w4[3].y;
        acc[i][2] += a[i].x * w4[0].z + a[i].y * w4[1].z + a[i].z * w4[2].z + a[i].w * w4[3].z;
        acc[i][3] += a[i].x * w4[0].w + a[i].y * w4[1].w + a[i].z * w4[2].w + a[i].w * w4[3].w;
      }
    }
  }
#pragma unroll
  for (int i = 0; i < 4; i++) {
#pragma unroll
    for (int j = 0; j < 4; j++) {
      const int row = row0 + rg * 4 + i;
      const int b = row >> 12;
      const int n = row & (N_ - 1);
      const int col = cg * 4 + j;
      const float val = acc[i][j] + bias[col];
      const size_t bh = (size_t)(b * H_ + hh);
      if (mz == 0)      q16[(bh * N_ + n) * DH_ + col] = f2bf(val);
      else if (mz == 1) k16[(bh * N_ + n) * DH_ + col] = f2bf(val);
      else              vT16[(bh * DH_ + col) * N_ + n] = f2bf(val);
    }
  }
}

// ---------------------------------------------------------------------------
// Kernel 3 (MFMA): invl[j] = 1 / sum_i exp(s_ij)     (scores bounded -> no max)
// grid: 512 blocks 1D; bh = blk&7 (XCD-locality), jblock = blk>>3 (64 cols).
// Wave w owns 16 columns. D = A(K)·B(Q^T): D[m=j][n=i].
// ---------------------------------------------------------------------------
__global__ __launch_bounds__(256) void colstats_kernel(
    const unsigned short* __restrict__ q16, const unsigned short* __restrict__ k16,
    float* __restrict__ invl) {
  const int blk = blockIdx.x;
  const int bh = blk & 7;
  const int j0 = (blk >> 3) * 64;
  const int t = threadIdx.x;
  const int w = t >> 6;
  const int lane = t & 63;
  const int c = lane & 15, quad = lane >> 4;

  // Q tile: 64 rows x 64 bf16 (128B rows), XOR-swizzled chunks of 16B
  __shared__ unsigned short Qs[64 * 64];

  bf16x8 ka0 = *(const bf16x8*)&k16[((size_t)bh * N_ + j0 + w * 16 + c) * DH_ + quad * 8];
  bf16x8 ka1 = *(const bf16x8*)&k16[((size_t)bh * N_ + j0 + w * 16 + c) * DH_ + 32 + quad * 8];

  float lsum[4] = {0.f, 0.f, 0.f, 0.f};

  for (int i0 = 0; i0 < N_; i0 += 64) {
    __syncthreads();
#pragma unroll
    for (int p = 0; p < 2; p++) {
      const int e = t + p * 256;
      const int row = e >> 3, ch = e & 7;
      bf16x8 v = *(const bf16x8*)&q16[((size_t)bh * N_ + i0 + row) * DH_ + ch * 8];
      *(bf16x8*)&Qs[row * 64 + ((ch ^ (row & 7)) * 8)] = v;
    }
    __syncthreads();
#pragma unroll
    for (int is = 0; is < 4; is++) {
      const int ir = is * 16 + c;
      bf16x8 qf0 = *(const bf16x8*)&Qs[ir * 64 + ((quad ^ (ir & 7)) * 8)];
      bf16x8 qf1 = *(const bf16x8*)&Qs[ir * 64 + (((4 + quad) ^ (ir & 7)) * 8)];
      f32x4 acc = {0.f, 0.f, 0.f, 0.f};
      acc = __builtin_amdgcn_mfma_f32_16x16x32_bf16(ka0, qf0, acc, 0, 0, 0);
      acc = __builtin_amdgcn_mfma_f32_16x16x32_bf16(ka1, qf1, acc, 0, 0, 0);
#pragma unroll
      for (int r = 0; r < 4; r++) lsum[r] += __expf(acc[r] * INV_DK_);
    }
  }
#pragma unroll
  for (int r = 0; r < 4; r++) {
    float s = lsum[r];
    s += __shfl_xor(s, 1); s += __shfl_xor(s, 2);
    s += __shfl_xor(s, 4); s += __shfl_xor(s, 8);
    if (c == 0) invl[(size_t)bh * N_ + j0 + w * 16 + quad * 4 + r] = 1.0f / s;
  }
}

// ---------------------------------------------------------------------------
// Kernel 4 (MFMA): O[i,d] = sum_j exp(s_ij)*invl[j] * V[j,d]
// grid: 512 blocks 1D; bh = blk&7, iblock = blk>>3 (64 rows). Wave w: 16 rows.
// S via MFMA (A=Q,B=K^T); P->bf16->per-wave LDS; PV via MFMA (A=P,B=V^T-tile).
// ---------------------------------------------------------------------------
__global__ __launch_bounds__(256) void attnout_kernel(
    const unsigned short* __restrict__ q16, const unsigned short* __restrict__ k16,
    const unsigned short* __restrict__ vT16, const float* __restrict__ invl,
    float* __restrict__ obuf) {
  const int blk = blockIdx.x;
  const int bh = blk & 7;
  const int b = bh >> 2, hh = bh & 3;
  const int i0 = (blk >> 3) * 64;
  const int t = threadIdx.x;
  const int w = t >> 6;
  const int lane = t & 63;
  const int c = lane & 15, quad = lane >> 4;

  __shared__ unsigned short Ks[32 * 64];      // 32 j-rows x 128B, XOR-swizzled
  __shared__ unsigned short Vs[64 * 32];      // 64 d-rows x 64B (natural balance)
  __shared__ unsigned short Ps[4 * 16 * 32];  // per-wave private 16i x 32j
  __shared__ float ilt[32];

  bf16x8 qa0 = *(const bf16x8*)&q16[((size_t)bh * N_ + i0 + w * 16 + c) * DH_ + quad * 8];
  bf16x8 qa1 = *(const bf16x8*)&q16[((size_t)bh * N_ + i0 + w * 16 + c) * DH_ + 32 + quad * 8];

  f32x4 of[4] = {{0.f,0.f,0.f,0.f},{0.f,0.f,0.f,0.f},{0.f,0.f,0.f,0.f},{0.f,0.f,0.f,0.f}};

  for (int j0 = 0; j0 < N_; j0 += 32) {
    __syncthreads();
    {
      const int row = t >> 3, ch = t & 7;   // K tile: 32 rows x 8 chunks
      bf16x8 kv = *(const bf16x8*)&k16[((size_t)bh * N_ + j0 + row) * DH_ + ch * 8];
      *(bf16x8*)&Ks[row * 64 + ((ch ^ (row & 7)) * 8)] = kv;
    }
    {
      const int row = t >> 2, ch = t & 3;   // V^T tile: 64 d-rows x 4 chunks
      bf16x8 vv = *(const bf16x8*)&vT16[((size_t)bh * DH_ + row) * N_ + j0 + ch * 8];
      *(bf16x8*)&Vs[row * 32 + ch * 8] = vv;
    }
    if (t < 32) ilt[t] = invl[(size_t)bh * N_ + j0 + t];
    __syncthreads();

#pragma unroll
    for (int jh = 0; jh < 2; jh++) {
      const int jr = jh * 16 + c;
      bf16x8 kf0 = *(const bf16x8*)&Ks[jr * 64 + ((quad ^ (jr & 7)) * 8)];
      bf16x8 kf1 = *(const bf16x8*)&Ks[jr * 64 + (((4 + quad) ^ (jr & 7)) * 8)];
      f32x4 sacc = {0.f, 0.f, 0.f, 0.f};
      sacc = __builtin_amdgcn_mfma_f32_16x16x32_bf16(qa0, kf0, sacc, 0, 0, 0);
      sacc = __builtin_amdgcn_mfma_f32_16x16x32_bf16(qa1, kf1, sacc, 0, 0, 0);
      const float il = ilt[jh * 16 + c];
#pragma unroll
      for (int r = 0; r < 4; r++) {
        const float p = __expf(sacc[r] * INV_DK_) * il;
        Ps[w * 512 + (quad * 4 + r) * 32 + jh * 16 + c] = f2bf(p);
      }
    }
    // Wave-private P round-trip: compiler orders LDS ops within the wave.
    bf16x8 pa = *(const bf16x8*)&Ps[w * 512 + c * 32 + quad * 8];
#pragma unroll
    for (int fo = 0; fo < 4; fo++) {
      bf16x8 vf = *(const bf16x8*)&Vs[(fo * 16 + c) * 32 + quad * 8];
      of[fo] = __builtin_amdgcn_mfma_f32_16x16x32_bf16(pa, vf, of[fo], 0, 0, 0);
    }
  }
#pragma unroll
  for (int fo = 0; fo < 4; fo++)
#pragma unroll
    for (int r = 0; r < 4; r++)
      obuf[((size_t)b * N_ + i0 + w * 16 + quad * 4 + r) * C_ + hh * DH_ + fo * 16 + c] = of[fo][r];
}

// ---------------------------------------------------------------------------
// Kernel 5: out = o @ Wo + bo    grid: (128, 4)   (fp32, unchanged)
// ---------------------------------------------------------------------------
__global__ __launch_bounds__(256) void outproj_kernel(
    const float* __restrict__ obuf, const float* __restrict__ Wo,
    const float* __restrict__ bo, float* __restrict__ out) {
  const int rt = blockIdx.x, ct = blockIdx.y;
  __shared__ float As[64][68];
  __shared__ float Ws[64][68];
  const int t = threadIdx.x;
  const int cg = t & 15, rg = t >> 4;

  float acc[4][4] = {};
  for (int kt = 0; kt < C_; kt += 64) {
    __syncthreads();
    for (int e = t; e < 4096; e += 256) {
      As[e >> 6][e & 63] = obuf[((size_t)rt * 64 + (e >> 6)) * C_ + kt + (e & 63)];
      Ws[e >> 6][e & 63] = Wo[((size_t)kt + (e >> 6)) * C_ + ct * 64 + (e & 63)];
    }
    __syncthreads();
    for (int k4 = 0; k4 < 64; k4 += 4) {
      float4 a[4], w4[4];
#pragma unroll
      for (int i = 0; i < 4; i++) a[i] = *(const float4*)&As[rg * 4 + i][k4];
#pragma unroll
      for (int kk = 0; kk < 4; kk++) w4[kk] = *(const float4*)&Ws[k4 + kk][cg * 4];
#pragma unroll
      for (int i = 0; i < 4; i++) {
        acc[i][0] += a[i].x * w4[0].x + a[i].y * w4[1].x + a[i].z * w4[2].x + a[i].w * w4[3].x;
        acc[i][1] += a[i].x * w4[0].y + a[i].y * w4[1].y + a[i].z * w4[2].y + a[i].w * w4[3].y;
        acc[i][2] += a[i].x * w4[0].z + a[i].y * w4[1].z + a[i].z * w4[2].z + a[i].w * w4[3].z;
        acc[i][3] += a[i].x * w4[0].w + a[i].y * w4[1].w + a[i].z * w4[2].w + a[i].w * w4[3].w;
      }
    }
  }
#pragma unroll
  for (int i = 0; i < 4; i++)
#pragma unroll
    for (int j = 0; j < 4; j++) {
      const int col = ct * 64 + cg * 4 + j;
      out[((size_t)rt * 64 + rg * 4 + i) * C_ + col] = acc[i][j] + bo[col];
    }
}

// ---------------------------------------------------------------------------
extern "C" void kernel_launch(void* const* d_in, const int* in_sizes, int n_in,
                              void* d_out, int out_size, void* d_ws, size_t ws_size,
                              hipStream_t stream) {
  const float* x    = (const float*)d_in[0];
  const float* pos  = (const float*)d_in[1];
  const float* Wq   = (const float*)d_in[2];
  const float* bq   = (const float*)d_in[3];
  const float* Wk   = (const float*)d_in[4];
  const float* bk   = (const float*)d_in[5];
  const float* Wv   = (const float*)d_in[6];
  const float* bv   = (const float*)d_in[7];
  const float* Wo   = (const float*)d_in[8];
  const float* bo   = (const float*)d_in[9];
  const float* ln_g = (const float*)d_in[10];
  const float* ln_b = (const float*)d_in[11];
  float* out = (float*)d_out;

  // Workspace: hbuf(2M f32) | ob(2M f32) | invl(32K f32) | q16,k16,vT16 (2M u16 each)
  float* ws = (float*)d_ws;
  const size_t SZ = (size_t)B_ * N_ * C_;   // 2M
  float* hbuf = ws;
  float* ob   = hbuf + SZ;
  float* invl = ob + SZ;
  unsigned short* q16  = (unsigned short*)(invl + (size_t)B_ * H_ * N_);
  unsigned short* k16  = q16 + SZ;
  unsigned short* vT16 = k16 + SZ;

  ln_kernel<<<B_ * N_, 256, 0, stream>>>(x, pos, ln_g, ln_b, hbuf);
  qkv_kernel<<<dim3(B_ * N_ / 64, H_, 3), 256, 0, stream>>>(
      hbuf, Wq, bq, Wk, bk, Wv, bv, q16, k16, vT16);
  colstats_kernel<<<512, 256, 0, stream>>>(q16, k16, invl);
  attnout_kernel<<<512, 256, 0, stream>>>(q16, k16, vT16, invl, ob);
  outproj_kernel<<<dim3(B_ * N_ / 64, C_ / 64), 256, 0, stream>>>(ob, Wo, bo, out);
}

// Round 3
// 245.514 us; speedup vs baseline: 5.8286x; 1.6728x over previous
//
#include <hip/hip_runtime.h>
#include <math.h>

// Problem constants
#define B_ 2
#define N_ 4096
#define C_ 256
#define H_ 4
#define DH_ 64
#define EPS_ 1e-6f
// 1/sqrt(DH) * log2(e), folded into Wq/bq so P = exp2(s) directly
#define SCALE_Q_ 0.18033688011112042f

typedef short bf16x8 __attribute__((ext_vector_type(8)));   // 8 bf16 in 4 VGPRs
typedef float f32x4 __attribute__((ext_vector_type(4)));

__device__ __forceinline__ unsigned short f2bf(float x) {
  unsigned int u = __float_as_uint(x);
  return (unsigned short)((u + 0x7FFFu + ((u >> 16) & 1u)) >> 16);  // RNE
}
__device__ __forceinline__ float bf2f(unsigned short u) {
  return __uint_as_float(((unsigned int)u) << 16);
}

// ---------------------------------------------------------------------------
// Kernel 1: h16 = bf16(LayerNorm(x + pos) * g + b)   one block per row
// ---------------------------------------------------------------------------
__global__ __launch_bounds__(256) void ln_kernel(
    const float* __restrict__ x, const float* __restrict__ pos,
    const float* __restrict__ g, const float* __restrict__ beta,
    unsigned short* __restrict__ h16) {
  const int row = blockIdx.x;
  const int t = threadIdx.x;
  const int w = t >> 6;
  float val = x[row * C_ + t] + pos[row * C_ + t];
  __shared__ float sm[8];
  float s = val;
  s += __shfl_xor(s, 1);  s += __shfl_xor(s, 2);  s += __shfl_xor(s, 4);
  s += __shfl_xor(s, 8);  s += __shfl_xor(s, 16); s += __shfl_xor(s, 32);
  if ((t & 63) == 0) sm[w] = s;
  __syncthreads();
  const float mu = (sm[0] + sm[1] + sm[2] + sm[3]) * (1.0f / C_);
  const float d = val - mu;
  float v = d * d;
  v += __shfl_xor(v, 1);  v += __shfl_xor(v, 2);  v += __shfl_xor(v, 4);
  v += __shfl_xor(v, 8);  v += __shfl_xor(v, 16); v += __shfl_xor(v, 32);
  if ((t & 63) == 0) sm[4 + w] = v;
  __syncthreads();
  const float var = (sm[4] + sm[5] + sm[6] + sm[7]) * (1.0f / C_);
  h16[row * C_ + t] = f2bf(d * rsqrtf(var + EPS_) * g[t] + beta[t]);
}

// ---------------------------------------------------------------------------
// Kernel 2: weight transpose+cast to bf16 B-frag layout [n][k].
//   W3T[h][192 n][256 k]  (n: 0-63 q [pre-scaled by SCALE_Q], 64-127 k, 128-191 v)
//   WoT[256 n][256 k]
// grid 128 x 256 thr, 8 elems/thread (196608 + 65536 = 262144 total)
// ---------------------------------------------------------------------------
__global__ __launch_bounds__(256) void wconv_kernel(
    const float* __restrict__ Wq, const float* __restrict__ Wk,
    const float* __restrict__ Wv, const float* __restrict__ Wo,
    unsigned short* __restrict__ W3T, unsigned short* __restrict__ WoT) {
  const int base = blockIdx.x * 2048;
#pragma unroll
  for (int p = 0; p < 8; p++) {
    const int idx = base + p * 256 + threadIdx.x;
    if (idx < 196608) {
      const int m = idx >> 14;           // 0..11
      const int rem = idx & 16383;
      const int c = rem >> 6, d = rem & 63;
      const int h = m / 3, kind = m - h * 3;
      const float* W = kind == 0 ? Wq : kind == 1 ? Wk : Wv;
      float v = W[h * 16384 + rem];
      if (kind == 0) v *= SCALE_Q_;
      W3T[(h * 192 + kind * 64 + d) * 256 + c] = f2bf(v);
    } else {
      const int widx = idx - 196608;     // < 65536
      const int k = widx >> 8, n = widx & 255;
      WoT[n * 256 + k] = f2bf(Wo[widx]);
    }
  }
}

// ---------------------------------------------------------------------------
// Kernel 3 (MFMA): q/k/v projections.  q16,k16: [bh][n][64]; vT16: [bh][64][N]
// grid (64 rowtiles of 128, H). Wave w owns 32 rows; all 192 out-cols.
// ---------------------------------------------------------------------------
__global__ __launch_bounds__(256) void qkv_kernel(
    const unsigned short* __restrict__ h16, const unsigned short* __restrict__ W3T,
    const float* __restrict__ bq, const float* __restrict__ bk,
    const float* __restrict__ bv,
    unsigned short* __restrict__ q16, unsigned short* __restrict__ k16,
    unsigned short* __restrict__ vT16) {
  const int rt = blockIdx.x;
  const int hh = blockIdx.y;
  const int t = threadIdx.x;
  const int w = t >> 6, lane = t & 63, c = lane & 15, quad = lane >> 4;
  __shared__ unsigned short Hs[128 * 64];   // 16 KB, XOR-swizzled 16B chunks
  __shared__ unsigned short Bs[192 * 64];   // 24 KB
  const int row0 = rt * 128;

  f32x4 acc[2][12];
#pragma unroll
  for (int mi = 0; mi < 2; mi++)
#pragma unroll
    for (int nt = 0; nt < 12; nt++) acc[mi][nt] = (f32x4){0.f, 0.f, 0.f, 0.f};

  for (int kt = 0; kt < C_; kt += 64) {
    __syncthreads();
#pragma unroll
    for (int p = 0; p < 4; p++) {
      const int e = t + p * 256;
      const int row = e >> 3, ch = e & 7;
      *(bf16x8*)&Hs[row * 64 + ((ch ^ (row & 7)) * 8)] =
          *(const bf16x8*)&h16[(size_t)(row0 + row) * C_ + kt + ch * 8];
    }
#pragma unroll
    for (int p = 0; p < 6; p++) {
      const int e = t + p * 256;
      const int row = e >> 3, ch = e & 7;
      *(bf16x8*)&Bs[row * 64 + ((ch ^ (row & 7)) * 8)] =
          *(const bf16x8*)&W3T[(size_t)(hh * 192 + row) * C_ + kt + ch * 8];
    }
    __syncthreads();
#pragma unroll
    for (int kh = 0; kh < 2; kh++) {
      bf16x8 a[2];
#pragma unroll
      for (int mi = 0; mi < 2; mi++) {
        const int i = w * 32 + mi * 16 + c;
        a[mi] = *(const bf16x8*)&Hs[i * 64 + (((kh * 4 + quad) ^ (i & 7)) * 8)];
      }
#pragma unroll
      for (int nt = 0; nt < 12; nt++) {
        const int n = nt * 16 + c;
        bf16x8 b = *(const bf16x8*)&Bs[n * 64 + (((kh * 4 + quad) ^ (n & 7)) * 8)];
        acc[0][nt] = __builtin_amdgcn_mfma_f32_16x16x32_bf16(a[0], b, acc[0][nt], 0, 0, 0);
        acc[1][nt] = __builtin_amdgcn_mfma_f32_16x16x32_bf16(a[1], b, acc[1][nt], 0, 0, 0);
      }
    }
  }
#pragma unroll
  for (int nt = 0; nt < 12; nt++) {
    const int kind = nt >> 2;
    const int col = (nt & 3) * 16 + c;
    const float bias = kind == 0 ? bq[hh * 64 + col] * SCALE_Q_
                     : kind == 1 ? bk[hh * 64 + col] : bv[hh * 64 + col];
#pragma unroll
    for (int mi = 0; mi < 2; mi++) {
#pragma unroll
      for (int r = 0; r < 4; r++) {
        const int gr = row0 + w * 32 + mi * 16 + quad * 4 + r;
        const int b = gr >> 12, n = gr & (N_ - 1);
        const size_t bh = (size_t)(b * H_ + hh);
        const unsigned short val = f2bf(acc[mi][nt][r] + bias);
        if (kind == 0)      q16[(bh * N_ + n) * DH_ + col] = val;
        else if (kind == 1) k16[(bh * N_ + n) * DH_ + col] = val;
        else                vT16[(bh * DH_ + col) * N_ + n] = val;
      }
    }
  }
}

// ---------------------------------------------------------------------------
// Kernel 4 (MFMA): column sums l_j = sum_i exp2(s~_ij), then scale vT16 *= 1/l
// grid 512: bh = blk&7 (XCD affinity), 64 cols each. Reg-prefetch of Q tiles.
// ---------------------------------------------------------------------------
__global__ __launch_bounds__(256) void colstats_kernel(
    const unsigned short* __restrict__ q16, const unsigned short* __restrict__ k16,
    unsigned short* __restrict__ vT16) {
  const int blk = blockIdx.x;
  const int bh = blk & 7;
  const int j0 = (blk >> 3) * 64;
  const int t = threadIdx.x;
  const int w = t >> 6, lane = t & 63, c = lane & 15, quad = lane >> 4;
  __shared__ unsigned short Qs[64 * 64];
  __shared__ float ilv[64];

  const size_t kbase = ((size_t)bh * N_ + j0 + w * 16 + c) * DH_;
  bf16x8 ka0 = *(const bf16x8*)&k16[kbase + quad * 8];
  bf16x8 ka1 = *(const bf16x8*)&k16[kbase + 32 + quad * 8];

  bf16x8 pre[2];
  auto loadQ = [&](int i0) {
#pragma unroll
    for (int p = 0; p < 2; p++) {
      const int e = t + p * 256;
      const int row = e >> 3, ch = e & 7;
      pre[p] = *(const bf16x8*)&q16[((size_t)bh * N_ + i0 + row) * DH_ + ch * 8];
    }
  };
  loadQ(0);

  float lsum[4] = {0.f, 0.f, 0.f, 0.f};
  for (int i0 = 0; i0 < N_; i0 += 64) {
    __syncthreads();
#pragma unroll
    for (int p = 0; p < 2; p++) {
      const int e = t + p * 256;
      const int row = e >> 3, ch = e & 7;
      *(bf16x8*)&Qs[row * 64 + ((ch ^ (row & 7)) * 8)] = pre[p];
    }
    __syncthreads();
    if (i0 + 64 < N_) loadQ(i0 + 64);
#pragma unroll
    for (int is = 0; is < 4; is++) {
      const int ir = is * 16 + c;
      bf16x8 qf0 = *(const bf16x8*)&Qs[ir * 64 + ((quad ^ (ir & 7)) * 8)];
      bf16x8 qf1 = *(const bf16x8*)&Qs[ir * 64 + (((4 + quad) ^ (ir & 7)) * 8)];
      f32x4 s = {0.f, 0.f, 0.f, 0.f};
      s = __builtin_amdgcn_mfma_f32_16x16x32_bf16(ka0, qf0, s, 0, 0, 0);
      s = __builtin_amdgcn_mfma_f32_16x16x32_bf16(ka1, qf1, s, 0, 0, 0);
#pragma unroll
      for (int r = 0; r < 4; r++) lsum[r] += exp2f(s[r]);
    }
  }
#pragma unroll
  for (int r = 0; r < 4; r++) {
    float s = lsum[r];
    s += __shfl_xor(s, 1); s += __shfl_xor(s, 2);
    s += __shfl_xor(s, 4); s += __shfl_xor(s, 8);
    if (c == 0) ilv[w * 16 + quad * 4 + r] = 1.0f / s;
  }
  __syncthreads();
  // Scale this block's private vT16 column slice in place: V~ = invl_j * V
#pragma unroll
  for (int p = 0; p < 2; p++) {
    const int e = t + p * 256;
    const int d = e >> 3, ch = e & 7;
    const size_t addr = ((size_t)bh * DH_ + d) * N_ + j0 + ch * 8;
    bf16x8 v = *(const bf16x8*)&vT16[addr];
#pragma unroll
    for (int jj = 0; jj < 8; jj++)
      v[jj] = (short)f2bf(bf2f((unsigned short)v[jj]) * ilv[ch * 8 + jj]);
    *(bf16x8*)&vT16[addr] = v;
  }
}

// ---------------------------------------------------------------------------
// Kernel 5 (MFMA): O[i,d] = sum_j exp2(s~_ij) * V~[j,d]; writes bf16 ob16[B,N,C]
// grid 512: bh = blk&7, 64 i-rows. j-tile 64, swizzled Ks/Vs/Ps, reg-prefetch.
// ---------------------------------------------------------------------------
__global__ __launch_bounds__(256) void attnout_kernel(
    const unsigned short* __restrict__ q16, const unsigned short* __restrict__ k16,
    const unsigned short* __restrict__ vT16, unsigned short* __restrict__ ob16) {
  const int blk = blockIdx.x;
  const int bh = blk & 7;
  const int bb = bh >> 2, hh = bh & 3;
  const int i0 = (blk >> 3) * 64;
  const int t = threadIdx.x;
  const int w = t >> 6, lane = t & 63, c = lane & 15, quad = lane >> 4;

  __shared__ unsigned short Ks[64 * 64];      // 8 KB swizzled
  __shared__ unsigned short Vs[64 * 64];      // 8 KB swizzled
  __shared__ unsigned short Ps[4 * 16 * 64];  // 8 KB, wave-private 16i x 64j

  const size_t qbase = ((size_t)bh * N_ + i0 + w * 16 + c) * DH_;
  bf16x8 qa0 = *(const bf16x8*)&q16[qbase + quad * 8];
  bf16x8 qa1 = *(const bf16x8*)&q16[qbase + 32 + quad * 8];

  bf16x8 kpre[2], vpre[2];
  auto loadKV = [&](int jt) {
#pragma unroll
    for (int p = 0; p < 2; p++) {
      const int e = t + p * 256;
      const int row = e >> 3, ch = e & 7;
      kpre[p] = *(const bf16x8*)&k16[((size_t)bh * N_ + jt + row) * DH_ + ch * 8];
      vpre[p] = *(const bf16x8*)&vT16[((size_t)bh * DH_ + row) * N_ + jt + ch * 8];
    }
  };
  loadKV(0);

  f32x4 of[4];
#pragma unroll
  for (int dt = 0; dt < 4; dt++) of[dt] = (f32x4){0.f, 0.f, 0.f, 0.f};

  for (int j0 = 0; j0 < N_; j0 += 64) {
    __syncthreads();
#pragma unroll
    for (int p = 0; p < 2; p++) {
      const int e = t + p * 256;
      const int row = e >> 3, ch = e & 7;
      *(bf16x8*)&Ks[row * 64 + ((ch ^ (row & 7)) * 8)] = kpre[p];
      *(bf16x8*)&Vs[row * 64 + ((ch ^ (row & 7)) * 8)] = vpre[p];
    }
    __syncthreads();
    if (j0 + 64 < N_) loadKV(j0 + 64);   // in flight during compute

#pragma unroll
    for (int jh = 0; jh < 4; jh++) {
      const int jr = jh * 16 + c;
      bf16x8 kf0 = *(const bf16x8*)&Ks[jr * 64 + ((quad ^ (jr & 7)) * 8)];
      bf16x8 kf1 = *(const bf16x8*)&Ks[jr * 64 + (((4 + quad) ^ (jr & 7)) * 8)];
      f32x4 s = {0.f, 0.f, 0.f, 0.f};
      s = __builtin_amdgcn_mfma_f32_16x16x32_bf16(qa0, kf0, s, 0, 0, 0);
      s = __builtin_amdgcn_mfma_f32_16x16x32_bf16(qa1, kf1, s, 0, 0, 0);
      const int chnk = jh * 2 + (c >> 3);
      const int cl = c & 7;
#pragma unroll
      for (int r = 0; r < 4; r++) {
        const int i = quad * 4 + r;
        Ps[w * 1024 + i * 64 + ((chnk ^ (i & 7)) * 8) + cl] = f2bf(exp2f(s[r]));
      }
    }
    // Wave-private P round-trip (no barrier needed)
#pragma unroll
    for (int kh = 0; kh < 2; kh++) {
      bf16x8 pa = *(const bf16x8*)&Ps[w * 1024 + c * 64 + (((kh * 4 + quad) ^ (c & 7)) * 8)];
#pragma unroll
      for (int dt = 0; dt < 4; dt++) {
        const int d = dt * 16 + c;
        bf16x8 vf = *(const bf16x8*)&Vs[d * 64 + (((kh * 4 + quad) ^ (d & 7)) * 8)];
        of[dt] = __builtin_amdgcn_mfma_f32_16x16x32_bf16(pa, vf, of[dt], 0, 0, 0);
      }
    }
  }
#pragma unroll
  for (int dt = 0; dt < 4; dt++)
#pragma unroll
    for (int r = 0; r < 4; r++)
      ob16[((size_t)bb * N_ + i0 + w * 16 + quad * 4 + r) * C_ + hh * DH_ + dt * 16 + c] =
          f2bf(of[dt][r]);
}

// ---------------------------------------------------------------------------
// Kernel 6 (MFMA): out = o @ Wo + bo  (fp32 out). grid 256 (32-row tiles).
// Wave w owns n-range [w*64, w*64+64).
// ---------------------------------------------------------------------------
__global__ __launch_bounds__(256) void outproj_kernel(
    const unsigned short* __restrict__ ob16, const unsigned short* __restrict__ WoT,
    const float* __restrict__ bo, float* __restrict__ out) {
  const int rt = blockIdx.x;
  const int t = threadIdx.x;
  const int w = t >> 6, lane = t & 63, c = lane & 15, quad = lane >> 4;
  __shared__ unsigned short As[32 * 64];    // 4 KB
  __shared__ unsigned short Bs[256 * 64];   // 32 KB

  f32x4 acc[2][4];
#pragma unroll
  for (int mt = 0; mt < 2; mt++)
#pragma unroll
    for (int nt = 0; nt < 4; nt++) acc[mt][nt] = (f32x4){0.f, 0.f, 0.f, 0.f};

  for (int kt = 0; kt < C_; kt += 64) {
    __syncthreads();
    {
      const int row = t >> 3, ch = t & 7;
      *(bf16x8*)&As[row * 64 + ((ch ^ (row & 7)) * 8)] =
          *(const bf16x8*)&ob16[((size_t)rt * 32 + row) * C_ + kt + ch * 8];
    }
#pragma unroll
    for (int p = 0; p < 8; p++) {
      const int e = t + p * 256;
      const int row = e >> 3, ch = e & 7;
      *(bf16x8*)&Bs[row * 64 + ((ch ^ (row & 7)) * 8)] =
          *(const bf16x8*)&WoT[(size_t)row * C_ + kt + ch * 8];
    }
    __syncthreads();
#pragma unroll
    for (int kh = 0; kh < 2; kh++) {
      bf16x8 a[2];
#pragma unroll
      for (int mt = 0; mt < 2; mt++) {
        const int i = mt * 16 + c;
        a[mt] = *(const bf16x8*)&As[i * 64 + (((kh * 4 + quad) ^ (i & 7)) * 8)];
      }
#pragma unroll
      for (int nt = 0; nt < 4; nt++) {
        const int n = w * 64 + nt * 16 + c;
        bf16x8 b = *(const bf16x8*)&Bs[n * 64 + (((kh * 4 + quad) ^ (n & 7)) * 8)];
        acc[0][nt] = __builtin_amdgcn_mfma_f32_16x16x32_bf16(a[0], b, acc[0][nt], 0, 0, 0);
        acc[1][nt] = __builtin_amdgcn_mfma_f32_16x16x32_bf16(a[1], b, acc[1][nt], 0, 0, 0);
      }
    }
  }
#pragma unroll
  for (int mt = 0; mt < 2; mt++)
#pragma unroll
    for (int nt = 0; nt < 4; nt++) {
      const int col = w * 64 + nt * 16 + c;
      const float bias = bo[col];
#pragma unroll
      for (int r = 0; r < 4; r++)
        out[((size_t)rt * 32 + mt * 16 + quad * 4 + r) * C_ + col] = acc[mt][nt][r] + bias;
    }
}

// ---------------------------------------------------------------------------
extern "C" void kernel_launch(void* const* d_in, const int* in_sizes, int n_in,
                              void* d_out, int out_size, void* d_ws, size_t ws_size,
                              hipStream_t stream) {
  const float* x    = (const float*)d_in[0];
  const float* pos  = (const float*)d_in[1];
  const float* Wq   = (const float*)d_in[2];
  const float* bq   = (const float*)d_in[3];
  const float* Wk   = (const float*)d_in[4];
  const float* bk   = (const float*)d_in[5];
  const float* Wv   = (const float*)d_in[6];
  const float* bv   = (const float*)d_in[7];
  const float* Wo   = (const float*)d_in[8];
  const float* bo   = (const float*)d_in[9];
  const float* ln_g = (const float*)d_in[10];
  const float* ln_b = (const float*)d_in[11];
  float* out = (float*)d_out;

  // Workspace (u16): h16|q16|k16|vT16|ob16 (2M each) | W3T 196608 | WoT 65536
  const size_t SZ = (size_t)B_ * N_ * C_;   // 2097152
  unsigned short* h16  = (unsigned short*)d_ws;
  unsigned short* q16  = h16 + SZ;
  unsigned short* k16  = q16 + SZ;
  unsigned short* vT16 = k16 + SZ;
  unsigned short* ob16 = vT16 + SZ;
  unsigned short* W3T  = ob16 + SZ;
  unsigned short* WoT  = W3T + (size_t)H_ * 192 * 256;

  ln_kernel<<<B_ * N_, 256, 0, stream>>>(x, pos, ln_g, ln_b, h16);
  wconv_kernel<<<128, 256, 0, stream>>>(Wq, Wk, Wv, Wo, W3T, WoT);
  qkv_kernel<<<dim3(64, H_), 256, 0, stream>>>(h16, W3T, bq, bk, bv, q16, k16, vT16);
  colstats_kernel<<<512, 256, 0, stream>>>(q16, k16, vT16);
  attnout_kernel<<<512, 256, 0, stream>>>(q16, k16, vT16, ob16);
  outproj_kernel<<<256, 256, 0, stream>>>(ob16, WoT, bo, out);
}

// Round 5
// 228.522 us; speedup vs baseline: 6.2620x; 1.0744x over previous
//
#include <hip/hip_runtime.h>
#include <math.h>

// Problem constants
#define B_ 2
#define N_ 4096
#define C_ 256
#define H_ 4
#define DH_ 64
#define EPS_ 1e-6f
// 1/sqrt(DH) * log2(e), folded into Wq/bq so P = exp2(s) directly
#define SCALE_Q_ 0.18033688011112042f

typedef short bf16x8 __attribute__((ext_vector_type(8)));   // 8 bf16 in 4 VGPRs
typedef float f32x4 __attribute__((ext_vector_type(4)));

// Only the HW-verified gfx950 builtin — NO __has_builtin (host pass returns
// false for target builtins; direct calls compile fine, R1-R3 prove it).
#define MFMA32(a, b, c) __builtin_amdgcn_mfma_f32_16x16x32_bf16(a, b, c, 0, 0, 0)

__device__ __forceinline__ unsigned short f2bf(float x) {
  unsigned int u = __float_as_uint(x);
  return (unsigned short)((u + 0x7FFFu + ((u >> 16) & 1u)) >> 16);  // RNE
}
__device__ __forceinline__ float bf2f(unsigned short u) {
  return __uint_as_float(((unsigned int)u) << 16);
}

// ---------------------------------------------------------------------------
// Kernel 1: h16 = bf16(LayerNorm(x + pos) * g + b)   one block per row
// ---------------------------------------------------------------------------
__global__ __launch_bounds__(256) void ln_kernel(
    const float* __restrict__ x, const float* __restrict__ pos,
    const float* __restrict__ g, const float* __restrict__ beta,
    unsigned short* __restrict__ h16) {
  const int row = blockIdx.x;
  const int t = threadIdx.x;
  const int w = t >> 6;
  float val = x[row * C_ + t] + pos[row * C_ + t];
  __shared__ float sm[8];
  float s = val;
  s += __shfl_xor(s, 1);  s += __shfl_xor(s, 2);  s += __shfl_xor(s, 4);
  s += __shfl_xor(s, 8);  s += __shfl_xor(s, 16); s += __shfl_xor(s, 32);
  if ((t & 63) == 0) sm[w] = s;
  __syncthreads();
  const float mu = (sm[0] + sm[1] + sm[2] + sm[3]) * (1.0f / C_);
  const float d = val - mu;
  float v = d * d;
  v += __shfl_xor(v, 1);  v += __shfl_xor(v, 2);  v += __shfl_xor(v, 4);
  v += __shfl_xor(v, 8);  v += __shfl_xor(v, 16); v += __shfl_xor(v, 32);
  if ((t & 63) == 0) sm[4 + w] = v;
  __syncthreads();
  const float var = (sm[4] + sm[5] + sm[6] + sm[7]) * (1.0f / C_);
  h16[row * C_ + t] = f2bf(d * rsqrtf(var + EPS_) * g[t] + beta[t]);
}

// ---------------------------------------------------------------------------
// Kernel 2: weight transpose+cast to bf16 B-frag layout [n][k].
// ---------------------------------------------------------------------------
__global__ __launch_bounds__(256) void wconv_kernel(
    const float* __restrict__ Wq, const float* __restrict__ Wk,
    const float* __restrict__ Wv, const float* __restrict__ Wo,
    unsigned short* __restrict__ W3T, unsigned short* __restrict__ WoT) {
  const int base = blockIdx.x * 2048;
#pragma unroll
  for (int p = 0; p < 8; p++) {
    const int idx = base + p * 256 + threadIdx.x;
    if (idx < 196608) {
      const int m = idx >> 14;           // 0..11
      const int rem = idx & 16383;
      const int c = rem >> 6, d = rem & 63;
      const int h = m / 3, kind = m - h * 3;
      const float* W = kind == 0 ? Wq : kind == 1 ? Wk : Wv;
      float v = W[h * 16384 + rem];
      if (kind == 0) v *= SCALE_Q_;
      W3T[(h * 192 + kind * 64 + d) * 256 + c] = f2bf(v);
    } else {
      const int widx = idx - 196608;     // < 65536
      const int k = widx >> 8, n = widx & 255;
      WoT[n * 256 + k] = f2bf(Wo[widx]);
    }
  }
}

// ---------------------------------------------------------------------------
// Kernel 3 (MFMA): q/k/v projections.  q16,k16: [bh][n][64]; vT16: [bh][64][N]
// ---------------------------------------------------------------------------
__global__ __launch_bounds__(256) void qkv_kernel(
    const unsigned short* __restrict__ h16, const unsigned short* __restrict__ W3T,
    const float* __restrict__ bq, const float* __restrict__ bk,
    const float* __restrict__ bv,
    unsigned short* __restrict__ q16, unsigned short* __restrict__ k16,
    unsigned short* __restrict__ vT16) {
  const int rt = blockIdx.x;
  const int hh = blockIdx.y;
  const int t = threadIdx.x;
  const int w = t >> 6, lane = t & 63, c = lane & 15, quad = lane >> 4;
  __shared__ unsigned short Hs[128 * 64];
  __shared__ unsigned short Bs[192 * 64];
  const int row0 = rt * 128;

  f32x4 acc[2][12];
#pragma unroll
  for (int mi = 0; mi < 2; mi++)
#pragma unroll
    for (int nt = 0; nt < 12; nt++) acc[mi][nt] = (f32x4){0.f, 0.f, 0.f, 0.f};

  for (int kt = 0; kt < C_; kt += 64) {
    __syncthreads();
#pragma unroll
    for (int p = 0; p < 4; p++) {
      const int e = t + p * 256;
      const int row = e >> 3, ch = e & 7;
      *(bf16x8*)&Hs[row * 64 + ((ch ^ (row & 7)) * 8)] =
          *(const bf16x8*)&h16[(size_t)(row0 + row) * C_ + kt + ch * 8];
    }
#pragma unroll
    for (int p = 0; p < 6; p++) {
      const int e = t + p * 256;
      const int row = e >> 3, ch = e & 7;
      *(bf16x8*)&Bs[row * 64 + ((ch ^ (row & 7)) * 8)] =
          *(const bf16x8*)&W3T[(size_t)(hh * 192 + row) * C_ + kt + ch * 8];
    }
    __syncthreads();
#pragma unroll
    for (int kh = 0; kh < 2; kh++) {
      bf16x8 a[2];
#pragma unroll
      for (int mi = 0; mi < 2; mi++) {
        const int i = w * 32 + mi * 16 + c;
        a[mi] = *(const bf16x8*)&Hs[i * 64 + (((kh * 4 + quad) ^ (i & 7)) * 8)];
      }
#pragma unroll
      for (int nt = 0; nt < 12; nt++) {
        const int n = nt * 16 + c;
        bf16x8 b = *(const bf16x8*)&Bs[n * 64 + (((kh * 4 + quad) ^ (n & 7)) * 8)];
        acc[0][nt] = MFMA32(a[0], b, acc[0][nt]);
        acc[1][nt] = MFMA32(a[1], b, acc[1][nt]);
      }
    }
  }
#pragma unroll
  for (int nt = 0; nt < 12; nt++) {
    const int kind = nt >> 2;
    const int col = (nt & 3) * 16 + c;
    const float bias = kind == 0 ? bq[hh * 64 + col] * SCALE_Q_
                     : kind == 1 ? bk[hh * 64 + col] : bv[hh * 64 + col];
#pragma unroll
    for (int mi = 0; mi < 2; mi++) {
#pragma unroll
      for (int r = 0; r < 4; r++) {
        const int gr = row0 + w * 32 + mi * 16 + quad * 4 + r;
        const int b = gr >> 12, n = gr & (N_ - 1);
        const size_t bh = (size_t)(b * H_ + hh);
        const unsigned short val = f2bf(acc[mi][nt][r] + bias);
        if (kind == 0)      q16[(bh * N_ + n) * DH_ + col] = val;
        else if (kind == 1) k16[(bh * N_ + n) * DH_ + col] = val;
        else                vT16[(bh * DH_ + col) * N_ + n] = val;
      }
    }
  }
}

// ---------------------------------------------------------------------------
// Kernel 4 (MFMA): l_j = sum_i exp2(s~_ij); vT16 *= 1/l in place.
// grid 512: bh = blk&7, 64 cols. K-frags in registers; waves split i (16 each
// per 64-i stage) -> Q-tile read once per block; cross-wave l-reduce via LDS.
// ---------------------------------------------------------------------------
__global__ __launch_bounds__(256, 2) void colstats_kernel(
    const unsigned short* __restrict__ q16, const unsigned short* __restrict__ k16,
    unsigned short* __restrict__ vT16) {
  const int blk = blockIdx.x;
  const int bh = blk & 7;
  const int j0 = (blk >> 3) * 64;
  const int t = threadIdx.x;
  const int w = t >> 6, lane = t & 63, c = lane & 15, quad = lane >> 4;
  __shared__ unsigned short Qs[64 * 64];
  __shared__ float Lp[4][64];
  __shared__ float ilv[64];

  // K A-frags in registers: rows j = j0 + jb*16 + c
  bf16x8 ka[4][2];
#pragma unroll
  for (int jb = 0; jb < 4; jb++) {
    const size_t kb = ((size_t)bh * N_ + j0 + jb * 16 + c) * DH_;
    ka[jb][0] = *(const bf16x8*)&k16[kb + quad * 8];
    ka[jb][1] = *(const bf16x8*)&k16[kb + 32 + quad * 8];
  }

  bf16x8 pre[2];
  auto loadQ = [&](int i0) {
#pragma unroll
    for (int p = 0; p < 2; p++) {
      const int e = t + p * 256;
      const int row = e >> 3, ch = e & 7;
      pre[p] = *(const bf16x8*)&q16[((size_t)bh * N_ + i0 + row) * DH_ + ch * 8];
    }
  };
  loadQ(0);

  f32x4 lsum[4];
#pragma unroll
  for (int jb = 0; jb < 4; jb++) lsum[jb] = (f32x4){0.f, 0.f, 0.f, 0.f};

  for (int i0 = 0; i0 < N_; i0 += 64) {
    __syncthreads();
#pragma unroll
    for (int p = 0; p < 2; p++) {
      const int e = t + p * 256;
      const int row = e >> 3, ch = e & 7;
      *(bf16x8*)&Qs[row * 64 + ((ch ^ (row & 7)) * 8)] = pre[p];
    }
    __syncthreads();
    if (i0 + 64 < N_) loadQ(i0 + 64);
    // wave w's private 16-i quarter: i = i0 + w*16 + c
    const int ir = w * 16 + c;
    bf16x8 qf0 = *(const bf16x8*)&Qs[ir * 64 + ((quad ^ (c & 7)) * 8)];
    bf16x8 qf1 = *(const bf16x8*)&Qs[ir * 64 + (((4 + quad) ^ (c & 7)) * 8)];
#pragma unroll
    for (int jb = 0; jb < 4; jb++) {
      f32x4 s = {0.f, 0.f, 0.f, 0.f};
      s = MFMA32(ka[jb][0], qf0, s);
      s = MFMA32(ka[jb][1], qf1, s);
#pragma unroll
      for (int r = 0; r < 4; r++) lsum[jb][r] += exp2f(s[r]);
    }
  }
#pragma unroll
  for (int jb = 0; jb < 4; jb++) {
#pragma unroll
    for (int r = 0; r < 4; r++) {
      float s = lsum[jb][r];
      s += __shfl_xor(s, 1); s += __shfl_xor(s, 2);
      s += __shfl_xor(s, 4); s += __shfl_xor(s, 8);
      if (c == 0) Lp[w][jb * 16 + quad * 4 + r] = s;
    }
  }
  __syncthreads();
  if (t < 64) ilv[t] = 1.0f / (Lp[0][t] + Lp[1][t] + Lp[2][t] + Lp[3][t]);
  __syncthreads();
  // Scale this block's private vT16 column slice in place: V~ = invl_j * V
#pragma unroll
  for (int p = 0; p < 2; p++) {
    const int e = t + p * 256;
    const int d = e >> 3, ch = e & 7;
    const size_t addr = ((size_t)bh * DH_ + d) * N_ + j0 + ch * 8;
    bf16x8 v = *(const bf16x8*)&vT16[addr];
#pragma unroll
    for (int jj = 0; jj < 8; jj++)
      v[jj] = (short)f2bf(bf2f((unsigned short)v[jj]) * ilv[ch * 8 + jj]);
    *(bf16x8*)&vT16[addr] = v;
  }
}

// ---------------------------------------------------------------------------
// Kernel 5 (MFMA, 16x16x32 only): O[i,d] = sum_j exp2(s~_ij) * V~[j,d]
// grid 512: bh = blk&7, 64 i-rows/block; j-stage 128, wave w owns j-window
// [w*32, w*32+32). S computed TRANSPOSED in two MFMA pairs with PERMUTED K-row
// fragments (m -> 8*(m>>2)+(m&3), +4) so lane's 8 P values form exactly the
// 16x16x32 A-frag (k=quad*8+jj). PV chains with zero data movement; K/V tiles
// read once per block. Ks swizzle uses (row>>2)&7 because jr&7 of the permuted
// sets only spans 0..3. Partial O reduced cross-wave via 16KB LDS at the end.
// ---------------------------------------------------------------------------
__global__ __launch_bounds__(256, 2) void attnout_kernel(
    const unsigned short* __restrict__ q16, const unsigned short* __restrict__ k16,
    const unsigned short* __restrict__ vT16, unsigned short* __restrict__ ob16) {
  const int blk = blockIdx.x;
  const int bh = blk & 7;
  const int bb = bh >> 2, hh = bh & 3;
  const int i0 = (blk >> 3) * 64;
  const int t = threadIdx.x;
  const int w = t >> 6, lane = t & 63, c = lane & 15, quad = lane >> 4;

  __shared__ unsigned short Ks[128 * 64];  // 16 KB [j][d], swz ch^((j>>2)&7)
  __shared__ unsigned short Vs[64 * 128];  // 16 KB [d][j], swz ch^(d&15)
  __shared__ float Rbuf[4096];             // 16 KB partial-O reduce buffer

  // Q B-frags, persistent: qa[ib][dh], rows i = i0 + ib*16 + c
  bf16x8 qa[4][2];
#pragma unroll
  for (int ib = 0; ib < 4; ib++) {
    const size_t qb = ((size_t)bh * N_ + i0 + ib * 16 + c) * DH_;
    qa[ib][0] = *(const bf16x8*)&q16[qb + quad * 8];
    qa[ib][1] = *(const bf16x8*)&q16[qb + 32 + quad * 8];
  }

  bf16x8 kpre[4], vpre[4];
  auto loadKV = [&](int jt) {
#pragma unroll
    for (int p = 0; p < 4; p++) {
      const int e = t + p * 256;
      kpre[p] = *(const bf16x8*)&k16[((size_t)bh * N_ + jt + (e >> 3)) * DH_ + (e & 7) * 8];
      vpre[p] = *(const bf16x8*)&vT16[((size_t)bh * DH_ + (e >> 4)) * N_ + jt + (e & 15) * 8];
    }
  };
  loadKV(0);

  f32x4 of[4][4];
#pragma unroll
  for (int ib = 0; ib < 4; ib++)
#pragma unroll
    for (int dt = 0; dt < 4; dt++) of[ib][dt] = (f32x4){0.f, 0.f, 0.f, 0.f};

  const int jw = w * 32;
  for (int jt = 0; jt < N_; jt += 128) {
    __syncthreads();
#pragma unroll
    for (int p = 0; p < 4; p++) {
      const int e = t + p * 256;
      { const int row = e >> 3, ch = e & 7;      // K: 128 rows x 8 chunks
        *(bf16x8*)&Ks[row * 64 + ((ch ^ ((row >> 2) & 7)) * 8)] = kpre[p]; }
      { const int row = e >> 4, ch = e & 15;     // V: 64 rows x 16 chunks
        *(bf16x8*)&Vs[row * 128 + ((ch ^ (row & 15)) * 8)] = vpre[p]; }
    }
    __syncthreads();
    if (jt + 128 < N_) loadKV(jt + 128);   // in flight during compute

    // Permuted K A-frags: set s: m=c -> j-local jw + 8*(c>>2) + s*4 + (c&3)
    bf16x8 kf[2][2];
#pragma unroll
    for (int s = 0; s < 2; s++) {
      const int jr = jw + ((c >> 2) * 8) + s * 4 + (c & 3);
      const int swz = (jr >> 2) & 7;
      kf[s][0] = *(const bf16x8*)&Ks[jr * 64 + ((quad ^ swz) * 8)];
      kf[s][1] = *(const bf16x8*)&Ks[jr * 64 + (((4 + quad) ^ swz) * 8)];
    }
    // V B-frags: B[n=d][k=jj32] = V~T[d][jw + quad*8 + jj]
    bf16x8 vf[4];
#pragma unroll
    for (int dt = 0; dt < 4; dt++) {
      const int d = dt * 16 + c;
      vf[dt] = *(const bf16x8*)&Vs[d * 128 + (((w * 4 + quad) ^ (d & 15)) * 8)];
    }

#pragma unroll
    for (int ib = 0; ib < 4; ib++) {
      // S^T halves: D[m][n=i=c]; set s covers j-local jw + 8*quad + s*4 + r
      f32x4 s0 = {0.f, 0.f, 0.f, 0.f}, s1 = {0.f, 0.f, 0.f, 0.f};
      s0 = MFMA32(kf[0][0], qa[ib][0], s0);
      s0 = MFMA32(kf[0][1], qa[ib][1], s0);
      s1 = MFMA32(kf[1][0], qa[ib][0], s1);
      s1 = MFMA32(kf[1][1], qa[ib][1], s1);
      // P A-frag: pf[jj] = P[i=c][j-local = jw + quad*8 + jj]
      bf16x8 pf;
#pragma unroll
      for (int r = 0; r < 4; r++) {
        pf[r]     = (short)f2bf(exp2f(s0[r]));
        pf[4 + r] = (short)f2bf(exp2f(s1[r]));
      }
#pragma unroll
      for (int dt = 0; dt < 4; dt++)
        of[ib][dt] = MFMA32(pf, vf[dt], of[ib][dt]);
    }
  }

  // Cross-wave reduce of partial O (waves hold disjoint j-subsets)
  for (int p = 1; p < 4; ++p) {
    __syncthreads();
    if (w == p) {
#pragma unroll
      for (int ib = 0; ib < 4; ib++)
#pragma unroll
        for (int dt = 0; dt < 4; dt++)
          *(f32x4*)&Rbuf[lane * 64 + (((ib * 4 + dt) ^ (lane & 15)) * 4)] = of[ib][dt];
    }
    __syncthreads();
    if (w == 0) {
#pragma unroll
      for (int ib = 0; ib < 4; ib++)
#pragma unroll
        for (int dt = 0; dt < 4; dt++)
          of[ib][dt] += *(const f32x4*)&Rbuf[lane * 64 + (((ib * 4 + dt) ^ (lane & 15)) * 4)];
    }
  }
  if (w == 0) {
#pragma unroll
    for (int ib = 0; ib < 4; ib++)
#pragma unroll
      for (int dt = 0; dt < 4; dt++)
#pragma unroll
        for (int r = 0; r < 4; r++)
          ob16[((size_t)bb * N_ + i0 + ib * 16 + quad * 4 + r) * C_ + hh * DH_ + dt * 16 + c] =
              f2bf(of[ib][dt][r]);
  }
}

// ---------------------------------------------------------------------------
// Kernel 6 (MFMA): out = o @ Wo + bo  (fp32 out). grid 256 (32-row tiles).
// ---------------------------------------------------------------------------
__global__ __launch_bounds__(256) void outproj_kernel(
    const unsigned short* __restrict__ ob16, const unsigned short* __restrict__ WoT,
    const float* __restrict__ bo, float* __restrict__ out) {
  const int rt = blockIdx.x;
  const int t = threadIdx.x;
  const int w = t >> 6, lane = t & 63, c = lane & 15, quad = lane >> 4;
  __shared__ unsigned short As[32 * 64];
  __shared__ unsigned short Bs[256 * 64];

  f32x4 acc[2][4];
#pragma unroll
  for (int mt = 0; mt < 2; mt++)
#pragma unroll
    for (int nt = 0; nt < 4; nt++) acc[mt][nt] = (f32x4){0.f, 0.f, 0.f, 0.f};

  for (int kt = 0; kt < C_; kt += 64) {
    __syncthreads();
    {
      const int row = t >> 3, ch = t & 7;
      *(bf16x8*)&As[row * 64 + ((ch ^ (row & 7)) * 8)] =
          *(const bf16x8*)&ob16[((size_t)rt * 32 + row) * C_ + kt + ch * 8];
    }
#pragma unroll
    for (int p = 0; p < 8; p++) {
      const int e = t + p * 256;
      const int row = e >> 3, ch = e & 7;
      *(bf16x8*)&Bs[row * 64 + ((ch ^ (row & 7)) * 8)] =
          *(const bf16x8*)&WoT[(size_t)row * C_ + kt + ch * 8];
    }
    __syncthreads();
#pragma unroll
    for (int kh = 0; kh < 2; kh++) {
      bf16x8 a[2];
#pragma unroll
      for (int mt = 0; mt < 2; mt++) {
        const int i = mt * 16 + c;
        a[mt] = *(const bf16x8*)&As[i * 64 + (((kh * 4 + quad) ^ (i & 7)) * 8)];
      }
#pragma unroll
      for (int nt = 0; nt < 4; nt++) {
        const int n = w * 64 + nt * 16 + c;
        bf16x8 b = *(const bf16x8*)&Bs[n * 64 + (((kh * 4 + quad) ^ (n & 7)) * 8)];
        acc[0][nt] = MFMA32(a[0], b, acc[0][nt]);
        acc[1][nt] = MFMA32(a[1], b, acc[1][nt]);
      }
    }
  }
#pragma unroll
  for (int mt = 0; mt < 2; mt++)
#pragma unroll
    for (int nt = 0; nt < 4; nt++) {
      const int col = w * 64 + nt * 16 + c;
      const float bias = bo[col];
#pragma unroll
      for (int r = 0; r < 4; r++)
        out[((size_t)rt * 32 + mt * 16 + quad * 4 + r) * C_ + col] = acc[mt][nt][r] + bias;
    }
}

// ---------------------------------------------------------------------------
extern "C" void kernel_launch(void* const* d_in, const int* in_sizes, int n_in,
                              void* d_out, int out_size, void* d_ws, size_t ws_size,
                              hipStream_t stream) {
  const float* x    = (const float*)d_in[0];
  const float* pos  = (const float*)d_in[1];
  const float* Wq   = (const float*)d_in[2];
  const float* bq   = (const float*)d_in[3];
  const float* Wk   = (const float*)d_in[4];
  const float* bk   = (const float*)d_in[5];
  const float* Wv   = (const float*)d_in[6];
  const float* bv   = (const float*)d_in[7];
  const float* Wo   = (const float*)d_in[8];
  const float* bo   = (const float*)d_in[9];
  const float* ln_g = (const float*)d_in[10];
  const float* ln_b = (const float*)d_in[11];
  float* out = (float*)d_out;

  // Workspace (u16): h16|q16|k16|vT16|ob16 (2M each) | W3T 196608 | WoT 65536
  const size_t SZ = (size_t)B_ * N_ * C_;   // 2097152
  unsigned short* h16  = (unsigned short*)d_ws;
  unsigned short* q16  = h16 + SZ;
  unsigned short* k16  = q16 + SZ;
  unsigned short* vT16 = k16 + SZ;
  unsigned short* ob16 = vT16 + SZ;
  unsigned short* W3T  = ob16 + SZ;
  unsigned short* WoT  = W3T + (size_t)H_ * 192 * 256;

  ln_kernel<<<B_ * N_, 256, 0, stream>>>(x, pos, ln_g, ln_b, h16);
  wconv_kernel<<<128, 256, 0, stream>>>(Wq, Wk, Wv, Wo, W3T, WoT);
  qkv_kernel<<<dim3(64, H_), 256, 0, stream>>>(h16, W3T, bq, bk, bv, q16, k16, vT16);
  colstats_kernel<<<512, 256, 0, stream>>>(q16, k16, vT16);
  attnout_kernel<<<512, 256, 0, stream>>>(q16, k16, vT16, ob16);
  outproj_kernel<<<256, 256, 0, stream>>>(ob16, WoT, bo, out);
}

// Round 7
// 195.480 us; speedup vs baseline: 7.3204x; 1.1690x over previous
//
#include <hip/hip_runtime.h>
#include <math.h>

// Problem constants
#define B_ 2
#define N_ 4096
#define C_ 256
#define H_ 4
#define DH_ 64
#define EPS_ 1e-6f
// 1/sqrt(DH) * log2(e), folded into Wq/bq so P = exp2(s) directly
#define SCALE_Q_ 0.18033688011112042f

typedef short bf16x8 __attribute__((ext_vector_type(8)));   // 8 bf16 in 4 VGPRs
typedef float f32x4 __attribute__((ext_vector_type(4)));
typedef int i32x4 __attribute__((ext_vector_type(4)));

// Only HW-verified gfx950 builtins, called directly — NO __has_builtin (host
// pass returns false for target builtins) and NO inline-asm trans ops (R6:
// v_exp_f32 via asm defeats the VALU_TRANS_USE_HAZARD recognizer -> stale
// register reads -> absmax 42.8).
#define MFMA32(a, b, c) __builtin_amdgcn_mfma_f32_16x16x32_bf16(a, b, c, 0, 0, 0)
#define FAST_EXP2(x) __builtin_amdgcn_exp2f(x)   // v_exp_f32, hazard-aware

__device__ __forceinline__ unsigned short f2bf(float x) {
  unsigned int u = __float_as_uint(x);
  return (unsigned short)((u + 0x7FFFu + ((u >> 16) & 1u)) >> 16);  // RNE
}
__device__ __forceinline__ float bf2f(unsigned short u) {
  return __uint_as_float(((unsigned int)u) << 16);
}
// Pack two floats to two bf16 (round-half-up) in one v_perm_b32.
__device__ __forceinline__ int pack2bf(float lo, float hi) {
  return (int)__builtin_amdgcn_perm(__float_as_uint(hi) + 0x8000u,
                                    __float_as_uint(lo) + 0x8000u, 0x07060302u);
}

// ---------------------------------------------------------------------------
// Kernel 1: h16 = bf16(LayerNorm(x + pos) * g + b)   one block per row
// ---------------------------------------------------------------------------
__global__ __launch_bounds__(256) void ln_kernel(
    const float* __restrict__ x, const float* __restrict__ pos,
    const float* __restrict__ g, const float* __restrict__ beta,
    unsigned short* __restrict__ h16) {
  const int row = blockIdx.x;
  const int t = threadIdx.x;
  const int w = t >> 6;
  float val = x[row * C_ + t] + pos[row * C_ + t];
  __shared__ float sm[8];
  float s = val;
  s += __shfl_xor(s, 1);  s += __shfl_xor(s, 2);  s += __shfl_xor(s, 4);
  s += __shfl_xor(s, 8);  s += __shfl_xor(s, 16); s += __shfl_xor(s, 32);
  if ((t & 63) == 0) sm[w] = s;
  __syncthreads();
  const float mu = (sm[0] + sm[1] + sm[2] + sm[3]) * (1.0f / C_);
  const float d = val - mu;
  float v = d * d;
  v += __shfl_xor(v, 1);  v += __shfl_xor(v, 2);  v += __shfl_xor(v, 4);
  v += __shfl_xor(v, 8);  v += __shfl_xor(v, 16); v += __shfl_xor(v, 32);
  if ((t & 63) == 0) sm[4 + w] = v;
  __syncthreads();
  const float var = (sm[4] + sm[5] + sm[6] + sm[7]) * (1.0f / C_);
  h16[row * C_ + t] = f2bf(d * rsqrtf(var + EPS_) * g[t] + beta[t]);
}

// ---------------------------------------------------------------------------
// Kernel 2: weight transpose+cast to bf16 B-frag layout [n][k].
// ---------------------------------------------------------------------------
__global__ __launch_bounds__(256) void wconv_kernel(
    const float* __restrict__ Wq, const float* __restrict__ Wk,
    const float* __restrict__ Wv, const float* __restrict__ Wo,
    unsigned short* __restrict__ W3T, unsigned short* __restrict__ WoT) {
  const int base = blockIdx.x * 2048;
#pragma unroll
  for (int p = 0; p < 8; p++) {
    const int idx = base + p * 256 + threadIdx.x;
    if (idx < 196608) {
      const int m = idx >> 14;           // 0..11
      const int rem = idx & 16383;
      const int c = rem >> 6, d = rem & 63;
      const int h = m / 3, kind = m - h * 3;
      const float* W = kind == 0 ? Wq : kind == 1 ? Wk : Wv;
      float v = W[h * 16384 + rem];
      if (kind == 0) v *= SCALE_Q_;
      W3T[(h * 192 + kind * 64 + d) * 256 + c] = f2bf(v);
    } else {
      const int widx = idx - 196608;     // < 65536
      const int k = widx >> 8, n = widx & 255;
      WoT[n * 256 + k] = f2bf(Wo[widx]);
    }
  }
}

// ---------------------------------------------------------------------------
// Kernel 3 (MFMA): q/k/v projections.  q16,k16: [bh][n][64]; vT16: [bh][64][N]
// ---------------------------------------------------------------------------
__global__ __launch_bounds__(256) void qkv_kernel(
    const unsigned short* __restrict__ h16, const unsigned short* __restrict__ W3T,
    const float* __restrict__ bq, const float* __restrict__ bk,
    const float* __restrict__ bv,
    unsigned short* __restrict__ q16, unsigned short* __restrict__ k16,
    unsigned short* __restrict__ vT16) {
  const int rt = blockIdx.x;
  const int hh = blockIdx.y;
  const int t = threadIdx.x;
  const int w = t >> 6, lane = t & 63, c = lane & 15, quad = lane >> 4;
  __shared__ unsigned short Hs[128 * 64];
  __shared__ unsigned short Bs[192 * 64];
  const int row0 = rt * 128;

  f32x4 acc[2][12];
#pragma unroll
  for (int mi = 0; mi < 2; mi++)
#pragma unroll
    for (int nt = 0; nt < 12; nt++) acc[mi][nt] = (f32x4){0.f, 0.f, 0.f, 0.f};

  for (int kt = 0; kt < C_; kt += 64) {
    __syncthreads();
#pragma unroll
    for (int p = 0; p < 4; p++) {
      const int e = t + p * 256;
      const int row = e >> 3, ch = e & 7;
      *(bf16x8*)&Hs[row * 64 + ((ch ^ (row & 7)) * 8)] =
          *(const bf16x8*)&h16[(size_t)(row0 + row) * C_ + kt + ch * 8];
    }
#pragma unroll
    for (int p = 0; p < 6; p++) {
      const int e = t + p * 256;
      const int row = e >> 3, ch = e & 7;
      *(bf16x8*)&Bs[row * 64 + ((ch ^ (row & 7)) * 8)] =
          *(const bf16x8*)&W3T[(size_t)(hh * 192 + row) * C_ + kt + ch * 8];
    }
    __syncthreads();
#pragma unroll
    for (int kh = 0; kh < 2; kh++) {
      bf16x8 a[2];
#pragma unroll
      for (int mi = 0; mi < 2; mi++) {
        const int i = w * 32 + mi * 16 + c;
        a[mi] = *(const bf16x8*)&Hs[i * 64 + (((kh * 4 + quad) ^ (i & 7)) * 8)];
      }
#pragma unroll
      for (int nt = 0; nt < 12; nt++) {
        const int n = nt * 16 + c;
        bf16x8 b = *(const bf16x8*)&Bs[n * 64 + (((kh * 4 + quad) ^ (n & 7)) * 8)];
        acc[0][nt] = MFMA32(a[0], b, acc[0][nt]);
        acc[1][nt] = MFMA32(a[1], b, acc[1][nt]);
      }
    }
  }
#pragma unroll
  for (int nt = 0; nt < 12; nt++) {
    const int kind = nt >> 2;
    const int col = (nt & 3) * 16 + c;
    const float bias = kind == 0 ? bq[hh * 64 + col] * SCALE_Q_
                     : kind == 1 ? bk[hh * 64 + col] : bv[hh * 64 + col];
#pragma unroll
    for (int mi = 0; mi < 2; mi++) {
#pragma unroll
      for (int r = 0; r < 4; r++) {
        const int gr = row0 + w * 32 + mi * 16 + quad * 4 + r;
        const int b = gr >> 12, n = gr & (N_ - 1);
        const size_t bh = (size_t)(b * H_ + hh);
        const unsigned short val = f2bf(acc[mi][nt][r] + bias);
        if (kind == 0)      q16[(bh * N_ + n) * DH_ + col] = val;
        else if (kind == 1) k16[(bh * N_ + n) * DH_ + col] = val;
        else                vT16[(bh * DH_ + col) * N_ + n] = val;
      }
    }
  }
}

// ---------------------------------------------------------------------------
// Kernel 4 (MFMA): l_j = sum_i exp2(s~_ij); vT16 *= 1/l in place.
// grid 512: bh = blk&7, 64 cols. K-frags in registers; waves split i (16 each
// per 64-i stage) -> Q-tile read once per block; cross-wave l-reduce via LDS.
// ---------------------------------------------------------------------------
__global__ __launch_bounds__(256, 2) void colstats_kernel(
    const unsigned short* __restrict__ q16, const unsigned short* __restrict__ k16,
    unsigned short* __restrict__ vT16) {
  const int blk = blockIdx.x;
  const int bh = blk & 7;
  const int j0 = (blk >> 3) * 64;
  const int t = threadIdx.x;
  const int w = t >> 6, lane = t & 63, c = lane & 15, quad = lane >> 4;
  __shared__ unsigned short Qs[64 * 64];
  __shared__ float Lp[4][64];
  __shared__ float ilv[64];

  // K A-frags in registers: rows j = j0 + jb*16 + c
  bf16x8 ka[4][2];
#pragma unroll
  for (int jb = 0; jb < 4; jb++) {
    const size_t kb = ((size_t)bh * N_ + j0 + jb * 16 + c) * DH_;
    ka[jb][0] = *(const bf16x8*)&k16[kb + quad * 8];
    ka[jb][1] = *(const bf16x8*)&k16[kb + 32 + quad * 8];
  }

  bf16x8 pre[2];
  auto loadQ = [&](int i0) {
#pragma unroll
    for (int p = 0; p < 2; p++) {
      const int e = t + p * 256;
      const int row = e >> 3, ch = e & 7;
      pre[p] = *(const bf16x8*)&q16[((size_t)bh * N_ + i0 + row) * DH_ + ch * 8];
    }
  };
  loadQ(0);

  f32x4 lsum[4];
#pragma unroll
  for (int jb = 0; jb < 4; jb++) lsum[jb] = (f32x4){0.f, 0.f, 0.f, 0.f};

  for (int i0 = 0; i0 < N_; i0 += 64) {
    __syncthreads();
#pragma unroll
    for (int p = 0; p < 2; p++) {
      const int e = t + p * 256;
      const int row = e >> 3, ch = e & 7;
      *(bf16x8*)&Qs[row * 64 + ((ch ^ (row & 7)) * 8)] = pre[p];
    }
    __syncthreads();
    if (i0 + 64 < N_) loadQ(i0 + 64);
    // wave w's private 16-i quarter: i = i0 + w*16 + c
    const int ir = w * 16 + c;
    bf16x8 qf0 = *(const bf16x8*)&Qs[ir * 64 + ((quad ^ (c & 7)) * 8)];
    bf16x8 qf1 = *(const bf16x8*)&Qs[ir * 64 + (((4 + quad) ^ (c & 7)) * 8)];
#pragma unroll
    for (int jb = 0; jb < 4; jb++) {
      f32x4 s = {0.f, 0.f, 0.f, 0.f};
      s = MFMA32(ka[jb][0], qf0, s);
      s = MFMA32(ka[jb][1], qf1, s);
#pragma unroll
      for (int r = 0; r < 4; r++) lsum[jb][r] += FAST_EXP2(s[r]);
    }
  }
#pragma unroll
  for (int jb = 0; jb < 4; jb++) {
#pragma unroll
    for (int r = 0; r < 4; r++) {
      float s = lsum[jb][r];
      s += __shfl_xor(s, 1); s += __shfl_xor(s, 2);
      s += __shfl_xor(s, 4); s += __shfl_xor(s, 8);
      if (c == 0) Lp[w][jb * 16 + quad * 4 + r] = s;
    }
  }
  __syncthreads();
  if (t < 64) ilv[t] = 1.0f / (Lp[0][t] + Lp[1][t] + Lp[2][t] + Lp[3][t]);
  __syncthreads();
  // Scale this block's private vT16 column slice in place: V~ = invl_j * V
#pragma unroll
  for (int p = 0; p < 2; p++) {
    const int e = t + p * 256;
    const int d = e >> 3, ch = e & 7;
    const size_t addr = ((size_t)bh * DH_ + d) * N_ + j0 + ch * 8;
    bf16x8 v = *(const bf16x8*)&vT16[addr];
#pragma unroll
    for (int jj = 0; jj < 8; jj++)
      v[jj] = (short)f2bf(bf2f((unsigned short)v[jj]) * ilv[ch * 8 + jj]);
    *(bf16x8*)&vT16[addr] = v;
  }
}

// ---------------------------------------------------------------------------
// Kernel 5 (MFMA, 16x16x32 only): O[i,d] = sum_j exp2(s~_ij) * V~[j,d]
// grid 512: bh = blk&7, 64 i-rows/block; j-stage 128, wave w owns j-window
// [w*32, w*32+32). S computed TRANSPOSED in two MFMA pairs with PERMUTED K-row
// fragments so lane's 8 P values form exactly the 16x16x32 A-frag. P via
// builtin v_exp_f32 + v_perm pair-pack (R5: precise exp2f was 52% VALUBusy).
// ---------------------------------------------------------------------------
__global__ __launch_bounds__(256, 2) void attnout_kernel(
    const unsigned short* __restrict__ q16, const unsigned short* __restrict__ k16,
    const unsigned short* __restrict__ vT16, unsigned short* __restrict__ ob16) {
  const int blk = blockIdx.x;
  const int bh = blk & 7;
  const int bb = bh >> 2, hh = bh & 3;
  const int i0 = (blk >> 3) * 64;
  const int t = threadIdx.x;
  const int w = t >> 6, lane = t & 63, c = lane & 15, quad = lane >> 4;

  __shared__ unsigned short Ks[128 * 64];  // 16 KB [j][d], swz ch^((j>>2)&7)
  __shared__ unsigned short Vs[64 * 128];  // 16 KB [d][j], swz ch^(d&15)
  __shared__ float Rbuf[4096];             // 16 KB partial-O reduce buffer

  // Q B-frags, persistent: qa[ib][dh], rows i = i0 + ib*16 + c
  bf16x8 qa[4][2];
#pragma unroll
  for (int ib = 0; ib < 4; ib++) {
    const size_t qb = ((size_t)bh * N_ + i0 + ib * 16 + c) * DH_;
    qa[ib][0] = *(const bf16x8*)&q16[qb + quad * 8];
    qa[ib][1] = *(const bf16x8*)&q16[qb + 32 + quad * 8];
  }

  bf16x8 kpre[4], vpre[4];
  auto loadKV = [&](int jt) {
#pragma unroll
    for (int p = 0; p < 4; p++) {
      const int e = t + p * 256;
      kpre[p] = *(const bf16x8*)&k16[((size_t)bh * N_ + jt + (e >> 3)) * DH_ + (e & 7) * 8];
      vpre[p] = *(const bf16x8*)&vT16[((size_t)bh * DH_ + (e >> 4)) * N_ + jt + (e & 15) * 8];
    }
  };
  loadKV(0);

  f32x4 of[4][4];
#pragma unroll
  for (int ib = 0; ib < 4; ib++)
#pragma unroll
    for (int dt = 0; dt < 4; dt++) of[ib][dt] = (f32x4){0.f, 0.f, 0.f, 0.f};

  const int jw = w * 32;
  for (int jt = 0; jt < N_; jt += 128) {
    __syncthreads();
#pragma unroll
    for (int p = 0; p < 4; p++) {
      const int e = t + p * 256;
      { const int row = e >> 3, ch = e & 7;      // K: 128 rows x 8 chunks
        *(bf16x8*)&Ks[row * 64 + ((ch ^ ((row >> 2) & 7)) * 8)] = kpre[p]; }
      { const int row = e >> 4, ch = e & 15;     // V: 64 rows x 16 chunks
        *(bf16x8*)&Vs[row * 128 + ((ch ^ (row & 15)) * 8)] = vpre[p]; }
    }
    __syncthreads();
    if (jt + 128 < N_) loadKV(jt + 128);   // in flight during compute

    // Permuted K A-frags: set s: m=c -> j-local jw + 8*(c>>2) + s*4 + (c&3)
    bf16x8 kf[2][2];
#pragma unroll
    for (int s = 0; s < 2; s++) {
      const int jr = jw + ((c >> 2) * 8) + s * 4 + (c & 3);
      const int swz = (jr >> 2) & 7;
      kf[s][0] = *(const bf16x8*)&Ks[jr * 64 + ((quad ^ swz) * 8)];
      kf[s][1] = *(const bf16x8*)&Ks[jr * 64 + (((4 + quad) ^ swz) * 8)];
    }
    // V B-frags: B[n=d][k=jj32] = V~T[d][jw + quad*8 + jj]
    bf16x8 vf[4];
#pragma unroll
    for (int dt = 0; dt < 4; dt++) {
      const int d = dt * 16 + c;
      vf[dt] = *(const bf16x8*)&Vs[d * 128 + (((w * 4 + quad) ^ (d & 15)) * 8)];
    }

#pragma unroll
    for (int ib = 0; ib < 4; ib++) {
      // S^T halves: D[m][n=i=c]; set s covers j-local jw + 8*quad + s*4 + r
      f32x4 s0 = {0.f, 0.f, 0.f, 0.f}, s1 = {0.f, 0.f, 0.f, 0.f};
      s0 = MFMA32(kf[0][0], qa[ib][0], s0);
      s0 = MFMA32(kf[0][1], qa[ib][1], s0);
      s1 = MFMA32(kf[1][0], qa[ib][0], s1);
      s1 = MFMA32(kf[1][1], qa[ib][1], s1);
      // P A-frag via v_exp + v_perm pair-pack: pf[jj] = P[i=c][jw+quad*8+jj]
      i32x4 pi;
      pi[0] = pack2bf(FAST_EXP2(s0[0]), FAST_EXP2(s0[1]));
      pi[1] = pack2bf(FAST_EXP2(s0[2]), FAST_EXP2(s0[3]));
      pi[2] = pack2bf(FAST_EXP2(s1[0]), FAST_EXP2(s1[1]));
      pi[3] = pack2bf(FAST_EXP2(s1[2]), FAST_EXP2(s1[3]));
      bf16x8 pf = *(bf16x8*)&pi;
#pragma unroll
      for (int dt = 0; dt < 4; dt++)
        of[ib][dt] = MFMA32(pf, vf[dt], of[ib][dt]);
    }
  }

  // Cross-wave reduce of partial O (waves hold disjoint j-subsets)
  for (int p = 1; p < 4; ++p) {
    __syncthreads();
    if (w == p) {
#pragma unroll
      for (int ib = 0; ib < 4; ib++)
#pragma unroll
        for (int dt = 0; dt < 4; dt++)
          *(f32x4*)&Rbuf[lane * 64 + (((ib * 4 + dt) ^ (lane & 15)) * 4)] = of[ib][dt];
    }
    __syncthreads();
    if (w == 0) {
#pragma unroll
      for (int ib = 0; ib < 4; ib++)
#pragma unroll
        for (int dt = 0; dt < 4; dt++)
          of[ib][dt] += *(const f32x4*)&Rbuf[lane * 64 + (((ib * 4 + dt) ^ (lane & 15)) * 4)];
    }
  }
  if (w == 0) {
#pragma unroll
    for (int ib = 0; ib < 4; ib++)
#pragma unroll
      for (int dt = 0; dt < 4; dt++)
#pragma unroll
        for (int r = 0; r < 4; r++)
          ob16[((size_t)bb * N_ + i0 + ib * 16 + quad * 4 + r) * C_ + hh * DH_ + dt * 16 + c] =
              f2bf(of[ib][dt][r]);
  }
}

// ---------------------------------------------------------------------------
// Kernel 6 (MFMA): out = o @ Wo + bo  (fp32 out). grid 256 (32-row tiles).
// ---------------------------------------------------------------------------
__global__ __launch_bounds__(256) void outproj_kernel(
    const unsigned short* __restrict__ ob16, const unsigned short* __restrict__ WoT,
    const float* __restrict__ bo, float* __restrict__ out) {
  const int rt = blockIdx.x;
  const int t = threadIdx.x;
  const int w = t >> 6, lane = t & 63, c = lane & 15, quad = lane >> 4;
  __shared__ unsigned short As[32 * 64];
  __shared__ unsigned short Bs[256 * 64];

  f32x4 acc[2][4];
#pragma unroll
  for (int mt = 0; mt < 2; mt++)
#pragma unroll
    for (int nt = 0; nt < 4; nt++) acc[mt][nt] = (f32x4){0.f, 0.f, 0.f, 0.f};

  for (int kt = 0; kt < C_; kt += 64) {
    __syncthreads();
    {
      const int row = t >> 3, ch = t & 7;
      *(bf16x8*)&As[row * 64 + ((ch ^ (row & 7)) * 8)] =
          *(const bf16x8*)&ob16[((size_t)rt * 32 + row) * C_ + kt + ch * 8];
    }
#pragma unroll
    for (int p = 0; p < 8; p++) {
      const int e = t + p * 256;
      const int row = e >> 3, ch = e & 7;
      *(bf16x8*)&Bs[row * 64 + ((ch ^ (row & 7)) * 8)] =
          *(const bf16x8*)&WoT[(size_t)row * C_ + kt + ch * 8];
    }
    __syncthreads();
#pragma unroll
    for (int kh = 0; kh < 2; kh++) {
      bf16x8 a[2];
#pragma unroll
      for (int mt = 0; mt < 2; mt++) {
        const int i = mt * 16 + c;
        a[mt] = *(const bf16x8*)&As[i * 64 + (((kh * 4 + quad) ^ (i & 7)) * 8)];
      }
#pragma unroll
      for (int nt = 0; nt < 4; nt++) {
        const int n = w * 64 + nt * 16 + c;
        bf16x8 b = *(const bf16x8*)&Bs[n * 64 + (((kh * 4 + quad) ^ (n & 7)) * 8)];
        acc[0][nt] = MFMA32(a[0], b, acc[0][nt]);
        acc[1][nt] = MFMA32(a[1], b, acc[1][nt]);
      }
    }
  }
#pragma unroll
  for (int mt = 0; mt < 2; mt++)
#pragma unroll
    for (int nt = 0; nt < 4; nt++) {
      const int col = w * 64 + nt * 16 + c;
      const float bias = bo[col];
#pragma unroll
      for (int r = 0; r < 4; r++)
        out[((size_t)rt * 32 + mt * 16 + quad * 4 + r) * C_ + col] = acc[mt][nt][r] + bias;
    }
}

// ---------------------------------------------------------------------------
extern "C" void kernel_launch(void* const* d_in, const int* in_sizes, int n_in,
                              void* d_out, int out_size, void* d_ws, size_t ws_size,
                              hipStream_t stream) {
  const float* x    = (const float*)d_in[0];
  const float* pos  = (const float*)d_in[1];
  const float* Wq   = (const float*)d_in[2];
  const float* bq   = (const float*)d_in[3];
  const float* Wk   = (const float*)d_in[4];
  const float* bk   = (const float*)d_in[5];
  const float* Wv   = (const float*)d_in[6];
  const float* bv   = (const float*)d_in[7];
  const float* Wo   = (const float*)d_in[8];
  const float* bo   = (const float*)d_in[9];
  const float* ln_g = (const float*)d_in[10];
  const float* ln_b = (const float*)d_in[11];
  float* out = (float*)d_out;

  // Workspace (u16): h16|q16|k16|vT16|ob16 (2M each) | W3T 196608 | WoT 65536
  const size_t SZ = (size_t)B_ * N_ * C_;   // 2097152
  unsigned short* h16  = (unsigned short*)d_ws;
  unsigned short* q16  = h16 + SZ;
  unsigned short* k16  = q16 + SZ;
  unsigned short* vT16 = k16 + SZ;
  unsigned short* ob16 = vT16 + SZ;
  unsigned short* W3T  = ob16 + SZ;
  unsigned short* WoT  = W3T + (size_t)H_ * 192 * 256;

  ln_kernel<<<B_ * N_, 256, 0, stream>>>(x, pos, ln_g, ln_b, h16);
  wconv_kernel<<<128, 256, 0, stream>>>(Wq, Wk, Wv, Wo, W3T, WoT);
  qkv_kernel<<<dim3(64, H_), 256, 0, stream>>>(h16, W3T, bq, bk, bv, q16, k16, vT16);
  colstats_kernel<<<512, 256, 0, stream>>>(q16, k16, vT16);
  attnout_kernel<<<512, 256, 0, stream>>>(q16, k16, vT16, ob16);
  outproj_kernel<<<256, 256, 0, stream>>>(ob16, WoT, bo, out);
}